// Round 19
// baseline (678.198 us; speedup 1.0000x reference)
//
#include <hip/hip_runtime.h>
#include <math.h>

#define N_NODES 6144
#define DIN 512
#define DHEAD 256
#define HID 512
#define DOUT 128
#define NPAIRS 16384
#define MW_ROW 96           // mask uint64 words per row
#define MB_ROW 768          // mask bytes per row
#define MWORDS (N_NODES*MW_ROW)

typedef __attribute__((ext_vector_type(8))) short bf16x8;
typedef __attribute__((ext_vector_type(4))) float f32x4;

static __device__ __forceinline__ float bf2f(unsigned short u){
  unsigned int x = ((unsigned int)u) << 16;
  return __builtin_bit_cast(float, x);
}
static __device__ __forceinline__ unsigned short f2bf(float f){
  unsigned int x = __builtin_bit_cast(unsigned int, f);
  x += 0x7FFFu + ((x >> 16) & 1u);   // RNE
  return (unsigned short)(x >> 16);
}
static __device__ __forceinline__ f32x4 mfma16(bf16x8 a, bf16x8 b, f32x4 c){
  return __builtin_amdgcn_mfma_f32_16x16x32_bf16(a, b, c, 0, 0, 0);
}

// ---------------- dtype detection (device-proven: flags={1,0}) ----------------
__global__ void detect_kernel(const unsigned int* __restrict__ xw,
                              const unsigned int* __restrict__ tsw,
                              int* __restrict__ flags){
  __shared__ int s_cnt; __shared__ unsigned int s_or;
  if (threadIdx.x == 0){ s_cnt = 0; s_or = 0u; }
  __syncthreads();
  int cnt = 0;
  for (int i = threadIdx.x; i < 4096; i += 256){
    unsigned int e = (xw[i] >> 7) & 0xFFu;
    cnt += (e > 100u && e < 150u) ? 1 : 0;
  }
  unsigned int ov = 0u;
  for (int i = threadIdx.x; i < 2048; i += 256) ov |= tsw[2*i + 1];
  atomicAdd(&s_cnt, cnt);
  atomicOr(&s_or, ov);
  __syncthreads();
  if (threadIdx.x == 0){
    flags[0] = (s_cnt < 2048) ? 1 : 0;
    flags[1] = (s_or == 0u) ? 1 : 0;
  }
}

// ---------------- conversions ----------------
__global__ void conv_bf16_kernel(const void* __restrict__ src, unsigned short* __restrict__ dst,
                                 int n, const int* __restrict__ flags){
  int i = blockIdx.x*256 + threadIdx.x;
  if (i >= n) return;
  dst[i] = flags[0] ? f2bf(((const float*)src)[i]) : ((const unsigned short*)src)[i];
}

// all 10 small f32 params in one launch; dst slots of 1024 floats each
__global__ void conv_small_kernel(const void* s0, const void* s1, const void* s2,
    const void* s3, const void* s4, const void* s5, const void* s6,
    const void* s7, const void* s8, const void* s9,
    float* __restrict__ dst, const int* __restrict__ flags){
  static const int lens[10] = {1024,512,1024,512,512,128,512,128,512,2};
  int slot = blockIdx.x >> 2;
  int idx = (blockIdx.x & 3)*256 + threadIdx.x;
  const void* srcs[10] = {s0,s1,s2,s3,s4,s5,s6,s7,s8,s9};
  if (idx < lens[slot]){
    const void* s = srcs[slot];
    dst[slot*1024 + idx] = flags[0] ? ((const float*)s)[idx]
                                    : bf2f(((const unsigned short*)s)[idx]);
  }
}

// all 6 weight transposes (K=512 each) in one launch; strip-blocked [K/32][Nn][32]
__global__ void conv_tr6_kernel(const void* s0, const void* s1, const void* s2,
    const void* s3, const void* s4, const void* s5,
    unsigned short* d0, unsigned short* d1, unsigned short* d2,
    unsigned short* d3, unsigned short* d4, unsigned short* d5,
    const int* __restrict__ flags){
  static const int bstart[6] = {0,1024,2048,3072,4096,4352};
  static const int NnT[6] = {256,256,512,512,128,128};
  int b = blockIdx.x;
  int e = 0;
  #pragma unroll
  for (int t = 1; t < 6; t++) if (b >= bstart[t]) e = t;
  const void* srcs[6] = {s0,s1,s2,s3,s4,s5};
  unsigned short* dsts[6] = {d0,d1,d2,d3,d4,d5};
  int Nn = NnT[e];
  int per = 512*Nn;
  long li = (long)(b - bstart[e])*256 + threadIdx.x;
  int bb = (int)(li / per); int i = (int)(li % per);
  int k = i / Nn, n = i % Nn;
  const void* s = srcs[e];
  unsigned short us = flags[0] ? f2bf(((const float*)s)[(long)bb*per + i])
                               : ((const unsigned short*)s)[(long)bb*per + i];
  dsts[e][(long)bb*per + (long)(k >> 5)*Nn*32 + (long)n*32 + (k & 31)] = us;
}

// ---------------- adjacency bitmask ----------------
__global__ void bitmask_kernel(const int* __restrict__ adj, unsigned long long* __restrict__ bm){
  int gid = blockIdx.x*blockDim.x + threadIdx.x;
  int l = gid & 63;
  int wv = gid >> 6;
  int nw = (gridDim.x*blockDim.x) >> 6;
  for (int word = wv; word < MWORDS; word += nw){
    int v = adj[(long)word*64 + l];
    unsigned long long mask = __ballot(v > 0);
    if (l == 0) bm[word] = mask;
  }
}

// ---------------- dense GEMM (strip-blocked B; batched A/B/bias/outB) ----------------
#define GEMM_BODY(CF) \
  int bb = blockIdx.z; \
  A += (long)bb*a_bstride; \
  BT += (long)bb*bt_bstride; \
  const float* bias_p = bias ? (bias + (long)bb*bias_bstride) : (const float*)0; \
  int w = threadIdx.x >> 6, l = threadIdx.x & 63; \
  int l15 = l & 15, lq = l >> 4; \
  int arow = blockIdx.x*64 + w*16 + l15; \
  int colbase = blockIdx.y * (CF*16); \
  f32x4 zero = {0.f,0.f,0.f,0.f}; \
  f32x4 acc[CF]; \
  _Pragma("unroll") \
  for (int i = 0; i < CF; i++) acc[i] = zero; \
  for (int kt = 0; kt < K; kt += 32){ \
    bf16x8 a = *(const bf16x8*)(A + (long)arow*K + kt + lq*8); \
    const unsigned short* bp = BT + (long)(kt >> 5)*bn*32 + lq*8; \
    _Pragma("unroll") \
    for (int cf = 0; cf < CF; cf++){ \
      bf16x8 b = *(const bf16x8*)(bp + (colbase + cf*16 + l15)*32); \
      acc[cf] = mfma16(a, b, acc[cf]); \
    } \
  } \
  int orow0 = blockIdx.x*64 + w*16 + lq*4; \
  _Pragma("unroll") \
  for (int reg = 0; reg < 4; reg++){ \
    int r = orow0 + reg; \
    _Pragma("unroll") \
    for (int cf = 0; cf < CF; cf++){ \
      int c = colbase + cf*16 + l15; \
      float v = acc[cf][reg]; \
      if (bias_p) v += bias_p[c]; \
      v = v > 0.f ? v : slope * v; \
      if (outF) outF[(long)bb*outF_bstride + (long)r*ldF + c] = v; \
      if (outB) outB[(long)bb*outB_bstride + (long)r*ldB + c] = f2bf(v); \
      if (outT) outT[(long)bb*outT_bstride + (long)(r >> 5)*ldT*32 + (long)c*32 + (r & 31)] = f2bf(v); \
    } \
  }

__global__ void gemm8_kernel(
    const unsigned short* __restrict__ A, long a_bstride,
    const unsigned short* __restrict__ BT, long bt_bstride,
    int K, int bn, const float* __restrict__ bias, long bias_bstride, float slope,
    float* __restrict__ outF, int ldF, long outF_bstride,
    unsigned short* __restrict__ outB, int ldB, long outB_bstride,
    unsigned short* __restrict__ outT, int ldT, long outT_bstride)
{ GEMM_BODY(8) }

__global__ void gemm4_kernel(
    const unsigned short* __restrict__ A, long a_bstride,
    const unsigned short* __restrict__ BT, long bt_bstride,
    int K, int bn, const float* __restrict__ bias, long bias_bstride, float slope,
    float* __restrict__ outF, int ldF, long outF_bstride,
    unsigned short* __restrict__ outB, int ldB, long outB_bstride,
    unsigned short* __restrict__ outT, int ldT, long outT_bstride)
{ GEMM_BODY(4) }

// ---------------- q,k GEMV (lean; no atomics) ----------------
__global__ void qk_kernel(const float* __restrict__ v,
    const float* __restrict__ avec, float* __restrict__ q, float* __restrict__ k){
  int h = blockIdx.y;
  v += (long)h*N_NODES*DHEAD; avec += h*2*DHEAD; q += (long)h*N_NODES; k += (long)h*N_NODES;
  int w = threadIdx.x >> 6, l = threadIdx.x & 63;
  int row = blockIdx.x*4 + w;
  float sq = 0.f, sk = 0.f;
  #pragma unroll
  for (int t = 0; t < 4; t++){
    int c = l + t*64;
    float vv = v[(long)row*DHEAD + c];
    sq += vv * avec[c];
    sk += vv * avec[DHEAD + c];
  }
  #pragma unroll
  for (int o = 32; o > 0; o >>= 1){ sq += __shfl_xor(sq, o, 64); sk += __shfl_xor(sk, o, 64); }
  if (l == 0){ q[row] = sq; k[row] = sk; }
}

// ---------------- per-head kmax: one block per head, deterministic ----------------
__global__ void kmax_kernel(const float* __restrict__ k, float* __restrict__ kmx){
  int h = blockIdx.y;
  k += (long)h*N_NODES;
  int t = threadIdx.x;
  float mx = -INFINITY;
  #pragma unroll
  for (int it = 0; it < 24; it++) mx = fmaxf(mx, k[t + it*256]);
  #pragma unroll
  for (int o = 32; o > 0; o >>= 1) mx = fmaxf(mx, __shfl_xor(mx, o, 64));
  __shared__ float red[4];
  if ((t & 63) == 0) red[t >> 6] = mx;
  __syncthreads();
  if (t == 0) kmx[h] = fmaxf(fmaxf(red[0], red[1]), fmaxf(red[2], red[3]));
}

// ---------------- full rowstat (fallback path only) ----------------
__global__ void rowstat_kernel(const float* __restrict__ q,
    const float* __restrict__ k, const unsigned long long* __restrict__ bm,
    float* __restrict__ m, float* __restrict__ d){
  int h = blockIdx.y;
  q += (long)h*N_NODES; k += (long)h*N_NODES; m += (long)h*N_NODES; d += (long)h*N_NODES;
  int i = blockIdx.x;
  int t = threadIdx.x;
  float qi = q[i];
  float sv[24];
  float smax = -INFINITY;
  #pragma unroll
  for (int it = 0; it < 24; it++){
    int j = t + it*256;
    unsigned long long wm = bm[(long)i*MW_ROW + (j >> 6)];
    float s = qi + k[j];
    s = s > 0.f ? s : 0.2f*s;
    s = ((wm >> (j & 63)) & 1ULL) ? s : -INFINITY;
    sv[it] = s;
    smax = fmaxf(smax, s);
  }
  __shared__ float red[4];
  __shared__ float red2[4];
  #pragma unroll
  for (int o = 32; o > 0; o >>= 1) smax = fmaxf(smax, __shfl_xor(smax, o, 64));
  if ((t & 63) == 0) red[t >> 6] = smax;
  __syncthreads();
  float bmax = fmaxf(fmaxf(red[0], red[1]), fmaxf(red[2], red[3]));
  float ssum = 0.f;
  #pragma unroll
  for (int it = 0; it < 24; it++) ssum += __expf(sv[it] - bmax);
  #pragma unroll
  for (int o = 32; o > 0; o >>= 1) ssum += __shfl_xor(ssum, o, 64);
  if ((t & 63) == 0) red2[t >> 6] = ssum;
  __syncthreads();
  if (t == 0){
    if (bmax == -INFINITY){ m[i] = 0.f; d[i] = 1.f; }
    else { m[i] = bmax; d[i] = red2[0]+red2[1]+red2[2]+red2[3]; }
  }
}

// ---------------- attn partial: J-step 64 (half the barriers); m'=lrelu(q+kmax) ----
__global__ void attn_part_kernel(
    const float* __restrict__ q, const float* __restrict__ k,
    const float* __restrict__ kmx,
    const unsigned char* __restrict__ mb,
    const unsigned short* __restrict__ vT,
    float* __restrict__ part,                // [slice][head][N][DHEAD] f32
    float* __restrict__ part_d,              // [slice][head][N] f32 row-sum partials
    int nstrips, int slices)                 // nstrips counts 64-j blocks
{
  __shared__ __align__(16) unsigned short pa[2][2][4][512];   // [buf][ks][rowgrp][512]
  int npair = 2*slices;
  int id = blockIdx.x;
  int pair = id % npair;
  int rowblk = id / npair;
  int h = pair % 2;
  int slice = pair / 2;

  q += (long)h*N_NODES; k += (long)h*N_NODES;
  vT += (long)h*DHEAD*N_NODES;

  int tid = threadIdx.x;
  int w = tid >> 6, l = tid & 63;
  int l15 = l & 15, lq = l >> 4;
  int blockbase = rowblk*64;

  int rp = blockbase + w*16 + l15;
  float qp = q[rp];
  float km = kmx[h];
  float mp = qp + km;  mp = mp > 0.f ? mp : 0.2f*mp;   // upper bound of row scores
  const unsigned char* mrow = mb + (long)rp*MB_ROW;

  int colw = w*64;
  const unsigned short* vbase = vT + (colw + l15)*32 + lq*8;
  int it0 = slice * nstrips;

  f32x4 zero = {0.f,0.f,0.f,0.f};
  f32x4 acc[4][4];
  #pragma unroll
  for (int g = 0; g < 4; g++)
    #pragma unroll
    for (int cf = 0; cf < 4; cf++) acc[g][cf] = zero;

  float psum = 0.f;

  bf16x8 bcur[8], bnxt[8];
  #pragma unroll
  for (int ks = 0; ks < 2; ks++)
    #pragma unroll
    for (int cf = 0; cf < 4; cf++)
      bcur[ks*4+cf] = *(const bf16x8*)(vbase + (long)(2*it0+ks)*(DHEAD*32) + cf*512);

  #define GENP_ALL(JT, DSTU) do { \
    int jb_ = (JT) + lq*8; \
    float4 ka_ = *(const float4*)(k + jb_); \
    float4 kb_ = *(const float4*)(k + jb_ + 4); \
    unsigned int mb_ = mrow[((JT) >> 3) + lq]; \
    float s_, e0_, e1_; \
    s_ = qp + ka_.x; s_ = s_>0.f? s_:0.2f*s_; e0_ = ((mb_>>0)&1u)? __expf(s_-mp):0.f; \
    s_ = qp + ka_.y; s_ = s_>0.f? s_:0.2f*s_; e1_ = ((mb_>>1)&1u)? __expf(s_-mp):0.f; \
    (DSTU).x = ((unsigned int)f2bf(e1_)<<16) | f2bf(e0_); \
    psum += e0_ + e1_; \
    s_ = qp + ka_.z; s_ = s_>0.f? s_:0.2f*s_; e0_ = ((mb_>>2)&1u)? __expf(s_-mp):0.f; \
    s_ = qp + ka_.w; s_ = s_>0.f? s_:0.2f*s_; e1_ = ((mb_>>3)&1u)? __expf(s_-mp):0.f; \
    (DSTU).y = ((unsigned int)f2bf(e1_)<<16) | f2bf(e0_); \
    psum += e0_ + e1_; \
    s_ = qp + kb_.x; s_ = s_>0.f? s_:0.2f*s_; e0_ = ((mb_>>4)&1u)? __expf(s_-mp):0.f; \
    s_ = qp + kb_.y; s_ = s_>0.f? s_:0.2f*s_; e1_ = ((mb_>>5)&1u)? __expf(s_-mp):0.f; \
    (DSTU).z = ((unsigned int)f2bf(e1_)<<16) | f2bf(e0_); \
    psum += e0_ + e1_; \
    s_ = qp + kb_.z; s_ = s_>0.f? s_:0.2f*s_; e0_ = ((mb_>>6)&1u)? __expf(s_-mp):0.f; \
    s_ = qp + kb_.w; s_ = s_>0.f? s_:0.2f*s_; e1_ = ((mb_>>7)&1u)? __expf(s_-mp):0.f; \
    (DSTU).w = ((unsigned int)f2bf(e1_)<<16) | f2bf(e0_); \
    psum += e0_ + e1_; \
  } while(0)

  // prologue: P(it0) both halves into pa[0]
  {
    uint4 ua, ub;
    GENP_ALL(it0*64, ua);
    GENP_ALL(it0*64 + 32, ub);
    *(uint4*)&pa[0][0][w][l*8] = ua;
    *(uint4*)&pa[0][1][w][l*8] = ub;
  }
  __syncthreads();

  for (int ii = 0; ii < nstrips; ++ii){
    int it = it0 + ii;
    bool have_next = (ii+1 < nstrips);
    if (have_next){
      #pragma unroll
      for (int ks = 0; ks < 2; ks++)
        #pragma unroll
        for (int cf = 0; cf < 4; cf++)
          bnxt[ks*4+cf] = *(const bf16x8*)(vbase + (long)(2*(it+1)+ks)*(DHEAD*32) + cf*512);
    }
    uint4 u1a, u1b;
    if (have_next){
      GENP_ALL((it+1)*64, u1a);
      GENP_ALL((it+1)*64 + 32, u1b);
    }
    __builtin_amdgcn_s_setprio(1);
    #pragma unroll
    for (int ks = 0; ks < 2; ks++){
      #pragma unroll
      for (int g = 0; g < 4; g++){
        bf16x8 ag = *(const bf16x8*)&pa[ii & 1][ks][g][l*8];
        #pragma unroll
        for (int cf = 0; cf < 4; cf++)
          acc[g][cf] = mfma16(ag, bcur[ks*4+cf], acc[g][cf]);
      }
    }
    __builtin_amdgcn_s_setprio(0);
    if (have_next){
      *(uint4*)&pa[(ii+1) & 1][0][w][l*8] = u1a;
      *(uint4*)&pa[(ii+1) & 1][1][w][l*8] = u1b;
    }
    __syncthreads();
    #pragma unroll
    for (int i2 = 0; i2 < 8; i2++) bcur[i2] = bnxt[i2];
  }
  #undef GENP_ALL

  psum += __shfl_xor(psum, 16, 64);
  psum += __shfl_xor(psum, 32, 64);
  if (lq == 0) part_d[(long)(slice*2 + h)*N_NODES + rp] = psum;

  float* pb = part + ((long)(slice*2 + h)*N_NODES)*DHEAD;
  #pragma unroll
  for (int g = 0; g < 4; g++){
    #pragma unroll
    for (int reg = 0; reg < 4; reg++){
      int r = blockbase + g*16 + lq*4 + reg;
      #pragma unroll
      for (int cf = 0; cf < 4; cf++){
        int c = colw + cf*16 + l15;
        pb[(long)r*DHEAD + c] = acc[g][cf][reg];
      }
    }
  }
}

// ---------------- attn combine (d from part_d slices) ----------------
__global__ void attn_combine_kernel(
    const float* __restrict__ part, const float* __restrict__ part_d,
    const float* __restrict__ bias, unsigned short* __restrict__ out,
    int do_elu, int slices)
{
  int h = blockIdx.y;
  int w = threadIdx.x >> 6, l = threadIdx.x & 63;
  int r = blockIdx.x*4 + w;
  float4 s = {0.f,0.f,0.f,0.f};
  float dsum = 0.f;
  for (int sl = 0; sl < slices; ++sl){
    float4 v = *(const float4*)&part[(((long)(sl*2 + h))*N_NODES + r)*DHEAD + l*4];
    s.x += v.x; s.y += v.y; s.z += v.z; s.w += v.w;
    dsum += part_d[(long)(sl*2 + h)*N_NODES + r];
  }
  float invd = 1.0f / fmaxf(dsum, 1e-30f);
  float o0 = s.x*invd, o1 = s.y*invd, o2 = s.z*invd, o3 = s.w*invd;
  o0 = o0 > 0.f ? o0 : 0.2f*o0;  o1 = o1 > 0.f ? o1 : 0.2f*o1;
  o2 = o2 > 0.f ? o2 : 0.2f*o2;  o3 = o3 > 0.f ? o3 : 0.2f*o3;
  float ss = o0*o0 + o1*o1 + o2*o2 + o3*o3;
  #pragma unroll
  for (int o = 32; o > 0; o >>= 1) ss += __shfl_xor(ss, o, 64);
  float invn = 1.0f / fmaxf(sqrtf(ss), 1e-12f);
  const float* bp = bias + h*DHEAD + l*4;
  float v0 = o0*invn + bp[0], v1 = o1*invn + bp[1], v2 = o2*invn + bp[2], v3 = o3*invn + bp[3];
  if (do_elu){
    v0 = v0 > 0.f ? v0 : expm1f(v0); v1 = v1 > 0.f ? v1 : expm1f(v1);
    v2 = v2 > 0.f ? v2 : expm1f(v2); v3 = v3 > 0.f ? v3 : expm1f(v3);
  }
  ushort4 r4;
  r4.x = f2bf(v0); r4.y = f2bf(v1); r4.z = f2bf(v2); r4.w = f2bf(v3);
  *(ushort4*)&out[(long)r*HID + h*DHEAD + l*4] = r4;
}

// ---------------- fallback attn (round-11, self-contained) ------------------------
__global__ void attn_kernel(
    const float* __restrict__ q, const float* __restrict__ k,
    const float* __restrict__ m, const float* __restrict__ d,
    const unsigned char* __restrict__ mb,
    const unsigned short* __restrict__ vT,
    const float* __restrict__ bias,
    unsigned short* __restrict__ out,
    int do_elu)
{
  __shared__ __align__(16) unsigned short pa[2][4][512];
  __shared__ float sred[4][64];
  int h = blockIdx.y;
  q += (long)h*N_NODES; k += (long)h*N_NODES; m += (long)h*N_NODES; d += (long)h*N_NODES;
  vT += (long)h*DHEAD*N_NODES;
  bias += h*DHEAD;
  int col_ofs = h*DHEAD;
  int tid = threadIdx.x;
  int w = tid >> 6, l = tid & 63;
  int l15 = l & 15, lq = l >> 4;
  int blockbase = blockIdx.x*64;
  int rp = blockbase + w*16 + l15;
  float qp = q[rp], mp = m[rp];
  const unsigned char* mrow = mb + (long)rp*MB_ROW;
  int colw = w*64;
  const unsigned short* vbase = vT + (colw + l15)*32 + lq*8;
  f32x4 zero = {0.f,0.f,0.f,0.f};
  f32x4 acc[4][4];
  #pragma unroll
  for (int g = 0; g < 4; g++)
    #pragma unroll
    for (int cf = 0; cf < 4; cf++) acc[g][cf] = zero;
  bf16x8 bcur[4], bnxt[4];
  #pragma unroll
  for (int cf = 0; cf < 4; cf++) bcur[cf] = *(const bf16x8*)(vbase + cf*512);
  const int NT = N_NODES/32;
  for (int it = 0; it < NT; ++it){
    int jt = it*32;
    if (it+1 < NT){
      const unsigned short* vb2 = vbase + (long)(it+1)*(DHEAD*32);
      #pragma unroll
      for (int cf = 0; cf < 4; cf++) bnxt[cf] = *(const bf16x8*)(vb2 + cf*512);
    }
    int jb = jt + lq*8;
    float4 ka = *(const float4*)(k + jb);
    float4 kb4 = *(const float4*)(k + jb + 4);
    unsigned int mb0 = mrow[(jt >> 3) + lq];
    bf16x8 a0;
    float s;
    #define GENP(KV,E) \
      s = qp + (KV); s = s > 0.f ? s : 0.2f*s; \
      a0[E] = (short)(((mb0 >> E) & 1u) ? f2bf(__expf(s - mp)) : (unsigned short)0);
    GENP(ka.x,0) GENP(ka.y,1) GENP(ka.z,2) GENP(ka.w,3)
    GENP(kb4.x,4) GENP(kb4.y,5) GENP(kb4.z,6) GENP(kb4.w,7)
    #undef GENP
    *(bf16x8*)&pa[it & 1][w][l*8] = a0;
    __syncthreads();
    #pragma unroll
    for (int g = 0; g < 4; g++){
      bf16x8 ag = *(const bf16x8*)&pa[it & 1][g][l*8];
      #pragma unroll
      for (int cf = 0; cf < 4; cf++)
        acc[g][cf] = mfma16(ag, bcur[cf], acc[g][cf]);
    }
    #pragma unroll
    for (int cf = 0; cf < 4; cf++) bcur[cf] = bnxt[cf];
  }
  #pragma unroll
  for (int g = 0; g < 4; g++){
    #pragma unroll
    for (int reg = 0; reg < 4; reg++){
      int rb = g*16 + lq*4 + reg;
      float invd = 1.0f / d[blockbase + rb];
      float ss = 0.f;
      #pragma unroll
      for (int cf = 0; cf < 4; cf++){
        float o = acc[g][cf][reg] * invd;
        o = o > 0.f ? o : 0.2f*o;
        acc[g][cf][reg] = o;
        ss += o*o;
      }
      #pragma unroll
      for (int o2 = 1; o2 < 16; o2 <<= 1) ss += __shfl_xor(ss, o2, 64);
      if (l15 == 0) sred[w][rb] = ss;
    }
  }
  __syncthreads();
  #pragma unroll
  for (int g = 0; g < 4; g++){
    #pragma unroll
    for (int reg = 0; reg < 4; reg++){
      int rb = g*16 + lq*4 + reg;
      int r = blockbase + rb;
      float tot = sred[0][rb] + sred[1][rb] + sred[2][rb] + sred[3][rb];
      float invn = 1.0f / fmaxf(sqrtf(tot), 1e-12f);
      #pragma unroll
      for (int cf = 0; cf < 4; cf++){
        int c = colw + cf*16 + l15;
        float o = acc[g][cf][reg]*invn + bias[c];
        if (do_elu) o = o > 0.f ? o : expm1f(o);
        out[(long)r*HID + col_ofs + c] = f2bf(o);
      }
    }
  }
}

// ---------------- gather pairs + tiny linear --> FLOAT32 output ----------------
__global__ void final_kernel(const void* __restrict__ ts,
    const float* __restrict__ tf, const float* __restrict__ tg,
    const float* __restrict__ linW, const float* __restrict__ linb,
    float* __restrict__ out, const int* __restrict__ flags)
{
  int w = threadIdx.x >> 6, l = threadIdx.x & 63;
  int b = blockIdx.x*4 + w;
  int i, j;
  if (flags[1]){ const long long* t64 = (const long long*)ts; i = (int)t64[2*b]; j = (int)t64[2*b+1]; }
  else { const int* t32 = (const int*)ts; i = t32[2*b]; j = t32[2*b+1]; }
  i = i < 0 ? 0 : (i >= N_NODES ? N_NODES-1 : i);
  j = j < 0 ? 0 : (j >= N_NODES ? N_NODES-1 : j);
  float t0 = tf[(long)i*DOUT + l],       t1 = tf[(long)i*DOUT + 64 + l];
  float g0 = tg[(long)j*DOUT + l],       g1 = tg[(long)j*DOUT + 64 + l];
  float p0 = t0*linW[2*l]   + t1*linW[2*(64+l)]   + g0*linW[2*(128+l)]   + g1*linW[2*(192+l)];
  float p1 = t0*linW[2*l+1] + t1*linW[2*(64+l)+1] + g0*linW[2*(128+l)+1] + g1*linW[2*(192+l)+1];
  #pragma unroll
  for (int o = 32; o > 0; o >>= 1){ p0 += __shfl_xor(p0, o, 64); p1 += __shfl_xor(p1, o, 64); }
  if (l == 0){
    out[2*b]   = p0 + linb[0];
    out[2*b+1] = p1 + linb[1];
  }
}

extern "C" void kernel_launch(void* const* d_in, const int* in_sizes, int n_in,
                              void* d_out, int out_size, void* d_ws, size_t ws_size,
                              hipStream_t stream){
  (void)in_sizes; (void)n_in; (void)out_size;
  const void* x    = d_in[0];
  const int*  adj  = (const int*)d_in[1];
  const void* ts   = d_in[2];
  const void* W1   = d_in[3];  const void* a1 = d_in[4];  const void* b1 = d_in[5];
  const void* W2   = d_in[6];  const void* a2 = d_in[7];  const void* b2 = d_in[8];
  const void* tf1W = d_in[9];  const void* tf1b = d_in[10];
  const void* tf2W = d_in[11]; const void* tf2b = d_in[12];
  const void* tg1W = d_in[13]; const void* tg1b = d_in[14];
  const void* tg2W = d_in[15]; const void* tg2b = d_in[16];
  const void* linW = d_in[17]; const void* linb = d_in[18];

  char* base = (char*)d_ws; size_t off = 0;
  auto alloc = [&](size_t bytes)->void*{
    void* r = base + off; off = (off + bytes + 255) & ~(size_t)255; return r;
  };
  int* flags                 = (int*)alloc(16);
  float* kmx                 = (float*)alloc(16);
  unsigned long long* bm     = (unsigned long long*)alloc((size_t)MWORDS*8);
  unsigned short* x_bf       = (unsigned short*)alloc((size_t)N_NODES*DIN*2);
  unsigned short* W1T        = (unsigned short*)alloc((size_t)2*DHEAD*DIN*2);
  unsigned short* W2T        = (unsigned short*)alloc((size_t)2*DHEAD*HID*2);
  unsigned short* mlp1WT     = (unsigned short*)alloc((size_t)2*HID*HID*2);
  unsigned short* mlp2WT     = (unsigned short*)alloc((size_t)2*HID*DOUT*2);
  float* smallf              = (float*)alloc(10*1024*4);
  float* v_f32           = (float*)alloc((size_t)2*N_NODES*DHEAD*4);
  unsigned short* vT_bf  = (unsigned short*)alloc((size_t)2*DHEAD*N_NODES*2);
  float* qv = (float*)alloc((size_t)2*N_NODES*4);
  float* kv = (float*)alloc((size_t)2*N_NODES*4);
  float* mv = (float*)alloc((size_t)2*N_NODES*4);
  float* dv = (float*)alloc((size_t)2*N_NODES*4);
  unsigned short* h_bf     = (unsigned short*)alloc((size_t)N_NODES*HID*2);
  unsigned short* embed_bf = (unsigned short*)alloc((size_t)N_NODES*HID*2);
  unsigned short* mid2     = (unsigned short*)alloc((size_t)2*N_NODES*HID*2);
  float* tfg = (float*)alloc((size_t)2*N_NODES*DOUT*4);
  size_t base_need = off;
  int ws_ok = (ws_size >= base_need) ? 1 : 0;

  // param views into smallf
  float* a1f  = smallf + 0*1024;
  float* b1f  = smallf + 1*1024;
  float* a2f  = smallf + 2*1024;
  float* b2f  = smallf + 3*1024;
  float* tf1bf = smallf + 4*1024;
  float* tf2bf = smallf + 5*1024;
  float* linWf = smallf + 8*1024;
  float* linbf = smallf + 9*1024;

  // j-split ladder (slices must divide 96)
  size_t per_slice = (size_t)2*N_NODES*DHEAD*4 + (size_t)2*N_NODES*4;
  int slices = 0;
  if      (ws_size >= base_need + 4*per_slice + 1024) slices = 4;
  else if (ws_size >= base_need + 2*per_slice + 1024) slices = 2;
  else if (ws_size >= base_need + 1*per_slice + 1024) slices = 1;
  float* part   = (slices > 0) ? (float*)alloc((size_t)slices*2*N_NODES*DHEAD*4) : nullptr;
  float* part_d = (slices > 0) ? (float*)alloc((size_t)slices*2*N_NODES*4) : nullptr;

  detect_kernel<<<1, 256, 0, stream>>>((const unsigned int*)x, (const unsigned int*)ts, flags);

  if (ws_ok){
    conv_bf16_kernel<<<(N_NODES*DIN)/256, 256, 0, stream>>>(x, x_bf, N_NODES*DIN, flags);
    conv_tr6_kernel<<<4608, 256, 0, stream>>>(W1, W2, tf1W, tg1W, tf2W, tg2W,
        W1T, W2T, mlp1WT, mlp1WT + (size_t)HID*HID, mlp2WT, mlp2WT + (size_t)HID*DOUT, flags);
    conv_small_kernel<<<40, 256, 0, stream>>>(a1, b1, a2, b2, tf1b, tf2b, tg1b, tg2b,
                                              linW, linb, smallf, flags);
    bitmask_kernel<<<2048, 256, 0, stream>>>(adj, bm);

    const unsigned char* mbytes = (const unsigned char*)bm;

    // ---- layer 1 ----
    gemm4_kernel<<<dim3(N_NODES/64, 4, 2), 256, 0, stream>>>(
        x_bf, 0, W1T, (long)DHEAD*DIN, DIN, DHEAD, nullptr, 0, 1.0f,
        v_f32, DHEAD, (long)N_NODES*DHEAD, nullptr, 0, 0,
        vT_bf, DHEAD, (long)DHEAD*N_NODES);
    qk_kernel<<<dim3(N_NODES/4, 2), 256, 0, stream>>>(v_f32, a1f, qv, kv);
    if (slices > 0){
      kmax_kernel<<<dim3(1, 2), 256, 0, stream>>>(kv, kmx);
      attn_part_kernel<<<(N_NODES/64)*2*slices, 256, 0, stream>>>(
          qv, kv, kmx, mbytes, vT_bf, part, part_d, (N_NODES/64)/slices, slices);
      attn_combine_kernel<<<dim3(N_NODES/4, 2), 256, 0, stream>>>(part, part_d, b1f, h_bf, 1, slices);
    } else {
      rowstat_kernel<<<dim3(N_NODES, 2), 256, 0, stream>>>(qv, kv, bm, mv, dv);
      attn_kernel<<<dim3(N_NODES/64, 2), 256, 0, stream>>>(qv, kv, mv, dv, mbytes, vT_bf, b1f, h_bf, 1);
    }

    // ---- layer 2 ----
    gemm4_kernel<<<dim3(N_NODES/64, 4, 2), 256, 0, stream>>>(
        h_bf, 0, W2T, (long)DHEAD*HID, HID, DHEAD, nullptr, 0, 1.0f,
        v_f32, DHEAD, (long)N_NODES*DHEAD, nullptr, 0, 0,
        vT_bf, DHEAD, (long)DHEAD*N_NODES);
    qk_kernel<<<dim3(N_NODES/4, 2), 256, 0, stream>>>(v_f32, a2f, qv, kv);
    if (slices > 0){
      kmax_kernel<<<dim3(1, 2), 256, 0, stream>>>(kv, kmx + 2);
      attn_part_kernel<<<(N_NODES/64)*2*slices, 256, 0, stream>>>(
          qv, kv, kmx + 2, mbytes, vT_bf, part, part_d, (N_NODES/64)/slices, slices);
      attn_combine_kernel<<<dim3(N_NODES/4, 2), 256, 0, stream>>>(part, part_d, b2f, embed_bf, 0, slices);
    } else {
      rowstat_kernel<<<dim3(N_NODES, 2), 256, 0, stream>>>(qv, kv, bm, mv, dv);
      attn_kernel<<<dim3(N_NODES/64, 2), 256, 0, stream>>>(qv, kv, mv, dv, mbytes, vT_bf, b2f, embed_bf, 0);
    }

    // ---- MLP heads: tf & tg batched via z ----
    gemm8_kernel<<<dim3(N_NODES/64, 4, 2), 256, 0, stream>>>(
        embed_bf, 0, mlp1WT, (long)HID*HID, HID, HID, tf1bf, 2048, 0.01f,
        nullptr, 0, 0, mid2, HID, (long)N_NODES*HID, nullptr, 0, 0);
    gemm4_kernel<<<dim3(N_NODES/64, 2, 2), 256, 0, stream>>>(
        mid2, (long)N_NODES*HID, mlp2WT, (long)HID*DOUT, HID, DOUT, tf2bf, 2048, 0.01f,
        tfg, DOUT, (long)N_NODES*DOUT, nullptr, 0, 0, nullptr, 0, 0);

    // ---- gather + linear (float32 output) ----
    final_kernel<<<NPAIRS/4, 256, 0, stream>>>(ts, tfg, tfg + (size_t)N_NODES*DOUT,
                                               linWf, linbf, (float*)d_out, flags);
  }
}

// Round 20
// 397.457 us; speedup vs baseline: 1.7063x; 1.7063x over previous
//
#include <hip/hip_runtime.h>
#include <math.h>

#define N_NODES 6144
#define DIN 512
#define DHEAD 256
#define HID 512
#define DOUT 128
#define NPAIRS 16384
#define MW_ROW 96           // mask uint64 words per row
#define MB_ROW 768          // mask bytes per row
#define MWORDS (N_NODES*MW_ROW)

typedef __attribute__((ext_vector_type(8))) short bf16x8;
typedef __attribute__((ext_vector_type(4))) float f32x4;

static __device__ __forceinline__ float bf2f(unsigned short u){
  unsigned int x = ((unsigned int)u) << 16;
  return __builtin_bit_cast(float, x);
}
static __device__ __forceinline__ unsigned short f2bf(float f){
  unsigned int x = __builtin_bit_cast(unsigned int, f);
  x += 0x7FFFu + ((x >> 16) & 1u);   // RNE
  return (unsigned short)(x >> 16);
}
static __device__ __forceinline__ f32x4 mfma16(bf16x8 a, bf16x8 b, f32x4 c){
  return __builtin_amdgcn_mfma_f32_16x16x32_bf16(a, b, c, 0, 0, 0);
}

// ---------------- dtype detection (device-proven: flags={1,0}) ----------------
__global__ void detect_kernel(const unsigned int* __restrict__ xw,
                              const unsigned int* __restrict__ tsw,
                              int* __restrict__ flags){
  __shared__ int s_cnt; __shared__ unsigned int s_or;
  if (threadIdx.x == 0){ s_cnt = 0; s_or = 0u; }
  __syncthreads();
  int cnt = 0;
  for (int i = threadIdx.x; i < 4096; i += 256){
    unsigned int e = (xw[i] >> 7) & 0xFFu;
    cnt += (e > 100u && e < 150u) ? 1 : 0;
  }
  unsigned int ov = 0u;
  for (int i = threadIdx.x; i < 2048; i += 256) ov |= tsw[2*i + 1];
  atomicAdd(&s_cnt, cnt);
  atomicOr(&s_or, ov);
  __syncthreads();
  if (threadIdx.x == 0){
    flags[0] = (s_cnt < 2048) ? 1 : 0;
    flags[1] = (s_or == 0u) ? 1 : 0;
  }
}

// ---------------- conversions ----------------
__global__ void conv_bf16_kernel(const void* __restrict__ src, unsigned short* __restrict__ dst,
                                 int n, const int* __restrict__ flags){
  int i = blockIdx.x*256 + threadIdx.x;
  if (i >= n) return;
  dst[i] = flags[0] ? f2bf(((const float*)src)[i]) : ((const unsigned short*)src)[i];
}

// all 10 small f32 params in one launch; dst slots of 1024 floats each
__global__ void conv_small_kernel(const void* s0, const void* s1, const void* s2,
    const void* s3, const void* s4, const void* s5, const void* s6,
    const void* s7, const void* s8, const void* s9,
    float* __restrict__ dst, const int* __restrict__ flags){
  static const int lens[10] = {1024,512,1024,512,512,128,512,128,512,2};
  int slot = blockIdx.x >> 2;
  int idx = (blockIdx.x & 3)*256 + threadIdx.x;
  const void* srcs[10] = {s0,s1,s2,s3,s4,s5,s6,s7,s8,s9};
  if (idx < lens[slot]){
    const void* s = srcs[slot];
    dst[slot*1024 + idx] = flags[0] ? ((const float*)s)[idx]
                                    : bf2f(((const unsigned short*)s)[idx]);
  }
}

// all 6 weight transposes (K=512 each) in one launch; strip-blocked [K/32][Nn][32]
__global__ void conv_tr6_kernel(const void* s0, const void* s1, const void* s2,
    const void* s3, const void* s4, const void* s5,
    unsigned short* d0, unsigned short* d1, unsigned short* d2,
    unsigned short* d3, unsigned short* d4, unsigned short* d5,
    const int* __restrict__ flags){
  static const int bstart[6] = {0,1024,2048,3072,4096,4352};
  static const int NnT[6] = {256,256,512,512,128,128};
  int b = blockIdx.x;
  int e = 0;
  #pragma unroll
  for (int t = 1; t < 6; t++) if (b >= bstart[t]) e = t;
  const void* srcs[6] = {s0,s1,s2,s3,s4,s5};
  unsigned short* dsts[6] = {d0,d1,d2,d3,d4,d5};
  int Nn = NnT[e];
  int per = 512*Nn;
  long li = (long)(b - bstart[e])*256 + threadIdx.x;
  int bb = (int)(li / per); int i = (int)(li % per);
  int k = i / Nn, n = i % Nn;
  const void* s = srcs[e];
  unsigned short us = flags[0] ? f2bf(((const float*)s)[(long)bb*per + i])
                               : ((const unsigned short*)s)[(long)bb*per + i];
  dsts[e][(long)bb*per + (long)(k >> 5)*Nn*32 + (long)n*32 + (k & 31)] = us;
}

// ---------------- adjacency bitmask ----------------
__global__ void bitmask_kernel(const int* __restrict__ adj, unsigned long long* __restrict__ bm){
  int gid = blockIdx.x*blockDim.x + threadIdx.x;
  int l = gid & 63;
  int wv = gid >> 6;
  int nw = (gridDim.x*blockDim.x) >> 6;
  for (int word = wv; word < MWORDS; word += nw){
    int v = adj[(long)word*64 + l];
    unsigned long long mask = __ballot(v > 0);
    if (l == 0) bm[word] = mask;
  }
}

// ---------------- dense GEMM (strip-blocked B; batched A/B/bias/outB) ----------------
#define GEMM_BODY(CF) \
  int bb = blockIdx.z; \
  A += (long)bb*a_bstride; \
  BT += (long)bb*bt_bstride; \
  const float* bias_p = bias ? (bias + (long)bb*bias_bstride) : (const float*)0; \
  int w = threadIdx.x >> 6, l = threadIdx.x & 63; \
  int l15 = l & 15, lq = l >> 4; \
  int arow = blockIdx.x*64 + w*16 + l15; \
  int colbase = blockIdx.y * (CF*16); \
  f32x4 zero = {0.f,0.f,0.f,0.f}; \
  f32x4 acc[CF]; \
  _Pragma("unroll") \
  for (int i = 0; i < CF; i++) acc[i] = zero; \
  for (int kt = 0; kt < K; kt += 32){ \
    bf16x8 a = *(const bf16x8*)(A + (long)arow*K + kt + lq*8); \
    const unsigned short* bp = BT + (long)(kt >> 5)*bn*32 + lq*8; \
    _Pragma("unroll") \
    for (int cf = 0; cf < CF; cf++){ \
      bf16x8 b = *(const bf16x8*)(bp + (colbase + cf*16 + l15)*32); \
      acc[cf] = mfma16(a, b, acc[cf]); \
    } \
  } \
  int orow0 = blockIdx.x*64 + w*16 + lq*4; \
  _Pragma("unroll") \
  for (int reg = 0; reg < 4; reg++){ \
    int r = orow0 + reg; \
    _Pragma("unroll") \
    for (int cf = 0; cf < CF; cf++){ \
      int c = colbase + cf*16 + l15; \
      float v = acc[cf][reg]; \
      if (bias_p) v += bias_p[c]; \
      v = v > 0.f ? v : slope * v; \
      if (outF) outF[(long)bb*outF_bstride + (long)r*ldF + c] = v; \
      if (outB) outB[(long)bb*outB_bstride + (long)r*ldB + c] = f2bf(v); \
      if (outT) outT[(long)bb*outT_bstride + (long)(r >> 5)*ldT*32 + (long)c*32 + (r & 31)] = f2bf(v); \
    } \
  }

__global__ void gemm8_kernel(
    const unsigned short* __restrict__ A, long a_bstride,
    const unsigned short* __restrict__ BT, long bt_bstride,
    int K, int bn, const float* __restrict__ bias, long bias_bstride, float slope,
    float* __restrict__ outF, int ldF, long outF_bstride,
    unsigned short* __restrict__ outB, int ldB, long outB_bstride,
    unsigned short* __restrict__ outT, int ldT, long outT_bstride)
{ GEMM_BODY(8) }

__global__ void gemm4_kernel(
    const unsigned short* __restrict__ A, long a_bstride,
    const unsigned short* __restrict__ BT, long bt_bstride,
    int K, int bn, const float* __restrict__ bias, long bias_bstride, float slope,
    float* __restrict__ outF, int ldF, long outF_bstride,
    unsigned short* __restrict__ outB, int ldB, long outB_bstride,
    unsigned short* __restrict__ outT, int ldT, long outT_bstride)
{ GEMM_BODY(4) }

// ---------------- q,k GEMV (lean; no atomics) ----------------
__global__ void qk_kernel(const float* __restrict__ v,
    const float* __restrict__ avec, float* __restrict__ q, float* __restrict__ k){
  int h = blockIdx.y;
  v += (long)h*N_NODES*DHEAD; avec += h*2*DHEAD; q += (long)h*N_NODES; k += (long)h*N_NODES;
  int w = threadIdx.x >> 6, l = threadIdx.x & 63;
  int row = blockIdx.x*4 + w;
  float sq = 0.f, sk = 0.f;
  #pragma unroll
  for (int t = 0; t < 4; t++){
    int c = l + t*64;
    float vv = v[(long)row*DHEAD + c];
    sq += vv * avec[c];
    sk += vv * avec[DHEAD + c];
  }
  #pragma unroll
  for (int o = 32; o > 0; o >>= 1){ sq += __shfl_xor(sq, o, 64); sk += __shfl_xor(sk, o, 64); }
  if (l == 0){ q[row] = sq; k[row] = sk; }
}

// ---------------- per-head kmax: one block per head, deterministic ----------------
__global__ void kmax_kernel(const float* __restrict__ k, float* __restrict__ kmx){
  int h = blockIdx.y;
  k += (long)h*N_NODES;
  int t = threadIdx.x;
  float mx = -INFINITY;
  #pragma unroll
  for (int it = 0; it < 24; it++) mx = fmaxf(mx, k[t + it*256]);
  #pragma unroll
  for (int o = 32; o > 0; o >>= 1) mx = fmaxf(mx, __shfl_xor(mx, o, 64));
  __shared__ float red[4];
  if ((t & 63) == 0) red[t >> 6] = mx;
  __syncthreads();
  if (t == 0) kmx[h] = fmaxf(fmaxf(red[0], red[1]), fmaxf(red[2], red[3]));
}

// ---------------- full rowstat (fallback path only) ----------------
__global__ void rowstat_kernel(const float* __restrict__ q,
    const float* __restrict__ k, const unsigned long long* __restrict__ bm,
    float* __restrict__ m, float* __restrict__ d){
  int h = blockIdx.y;
  q += (long)h*N_NODES; k += (long)h*N_NODES; m += (long)h*N_NODES; d += (long)h*N_NODES;
  int i = blockIdx.x;
  int t = threadIdx.x;
  float qi = q[i];
  float sv[24];
  float smax = -INFINITY;
  #pragma unroll
  for (int it = 0; it < 24; it++){
    int j = t + it*256;
    unsigned long long wm = bm[(long)i*MW_ROW + (j >> 6)];
    float s = qi + k[j];
    s = s > 0.f ? s : 0.2f*s;
    s = ((wm >> (j & 63)) & 1ULL) ? s : -INFINITY;
    sv[it] = s;
    smax = fmaxf(smax, s);
  }
  __shared__ float red[4];
  __shared__ float red2[4];
  #pragma unroll
  for (int o = 32; o > 0; o >>= 1) smax = fmaxf(smax, __shfl_xor(smax, o, 64));
  if ((t & 63) == 0) red[t >> 6] = smax;
  __syncthreads();
  float bmax = fmaxf(fmaxf(red[0], red[1]), fmaxf(red[2], red[3]));
  float ssum = 0.f;
  #pragma unroll
  for (int it = 0; it < 24; it++) ssum += __expf(sv[it] - bmax);
  #pragma unroll
  for (int o = 32; o > 0; o >>= 1) ssum += __shfl_xor(ssum, o, 64);
  if ((t & 63) == 0) red2[t >> 6] = ssum;
  __syncthreads();
  if (t == 0){
    if (bmax == -INFINITY){ m[i] = 0.f; d[i] = 1.f; }
    else { m[i] = bmax; d[i] = red2[0]+red2[1]+red2[2]+red2[3]; }
  }
}

// ---------------- attn partial: shift-invariant m' = lrelu(q+kmax); fused d --------
__global__ void attn_part_kernel(
    const float* __restrict__ q, const float* __restrict__ k,
    const float* __restrict__ kmx,
    const unsigned char* __restrict__ mb,
    const unsigned short* __restrict__ vT,
    float* __restrict__ part,                // [slice][head][N][DHEAD] f32
    float* __restrict__ part_d,              // [slice][head][N] f32 row-sum partials
    int nstrips, int slices)
{
  __shared__ __align__(16) unsigned short pa[2][4][512];
  int npair = 2*slices;
  int id = blockIdx.x;
  int pair = id % npair;
  int rowblk = id / npair;
  int h = pair % 2;
  int slice = pair / 2;

  q += (long)h*N_NODES; k += (long)h*N_NODES;
  vT += (long)h*DHEAD*N_NODES;

  int tid = threadIdx.x;
  int w = tid >> 6, l = tid & 63;
  int l15 = l & 15, lq = l >> 4;
  int blockbase = rowblk*64;

  int rp = blockbase + w*16 + l15;
  float qp = q[rp];
  float km = kmx[h];
  float mp = qp + km;  mp = mp > 0.f ? mp : 0.2f*mp;   // upper bound of row scores
  const unsigned char* mrow = mb + (long)rp*MB_ROW;

  int colw = w*64;
  const unsigned short* vbase = vT + (colw + l15)*32 + lq*8;
  int it0 = slice * nstrips;

  f32x4 zero = {0.f,0.f,0.f,0.f};
  f32x4 acc[4][4];
  #pragma unroll
  for (int g = 0; g < 4; g++)
    #pragma unroll
    for (int cf = 0; cf < 4; cf++) acc[g][cf] = zero;

  float psum = 0.f;

  bf16x8 bcur[4], bnxt[4];
  #pragma unroll
  for (int cf = 0; cf < 4; cf++)
    bcur[cf] = *(const bf16x8*)(vbase + (long)it0*(DHEAD*32) + cf*512);

  #define GENP_ALL(JT, DSTU) do { \
    int jb_ = (JT) + lq*8; \
    float4 ka_ = *(const float4*)(k + jb_); \
    float4 kb_ = *(const float4*)(k + jb_ + 4); \
    unsigned int mb_ = mrow[((JT) >> 3) + lq]; \
    float s_, e0_, e1_; \
    s_ = qp + ka_.x; s_ = s_>0.f? s_:0.2f*s_; e0_ = ((mb_>>0)&1u)? __expf(s_-mp):0.f; \
    s_ = qp + ka_.y; s_ = s_>0.f? s_:0.2f*s_; e1_ = ((mb_>>1)&1u)? __expf(s_-mp):0.f; \
    (DSTU).x = ((unsigned int)f2bf(e1_)<<16) | f2bf(e0_); \
    psum += e0_ + e1_; \
    s_ = qp + ka_.z; s_ = s_>0.f? s_:0.2f*s_; e0_ = ((mb_>>2)&1u)? __expf(s_-mp):0.f; \
    s_ = qp + ka_.w; s_ = s_>0.f? s_:0.2f*s_; e1_ = ((mb_>>3)&1u)? __expf(s_-mp):0.f; \
    (DSTU).y = ((unsigned int)f2bf(e1_)<<16) | f2bf(e0_); \
    psum += e0_ + e1_; \
    s_ = qp + kb_.x; s_ = s_>0.f? s_:0.2f*s_; e0_ = ((mb_>>4)&1u)? __expf(s_-mp):0.f; \
    s_ = qp + kb_.y; s_ = s_>0.f? s_:0.2f*s_; e1_ = ((mb_>>5)&1u)? __expf(s_-mp):0.f; \
    (DSTU).z = ((unsigned int)f2bf(e1_)<<16) | f2bf(e0_); \
    psum += e0_ + e1_; \
    s_ = qp + kb_.z; s_ = s_>0.f? s_:0.2f*s_; e0_ = ((mb_>>6)&1u)? __expf(s_-mp):0.f; \
    s_ = qp + kb_.w; s_ = s_>0.f? s_:0.2f*s_; e1_ = ((mb_>>7)&1u)? __expf(s_-mp):0.f; \
    (DSTU).w = ((unsigned int)f2bf(e1_)<<16) | f2bf(e0_); \
    psum += e0_ + e1_; \
  } while(0)

  {
    uint4 u0;
    GENP_ALL(it0*32, u0);
    *(uint4*)&pa[0][w][l*8] = u0;
  }
  __syncthreads();

  for (int ii = 0; ii < nstrips; ++ii){
    int it = it0 + ii;
    bool have_next = (ii+1 < nstrips);
    if (have_next){
      const unsigned short* vb2 = vbase + (long)(it+1)*(DHEAD*32);
      #pragma unroll
      for (int cf = 0; cf < 4; cf++) bnxt[cf] = *(const bf16x8*)(vb2 + cf*512);
    }
    uint4 u1;
    if (have_next) GENP_ALL((it+1)*32, u1);
    __builtin_amdgcn_s_setprio(1);
    #pragma unroll
    for (int g = 0; g < 4; g++){
      bf16x8 ag = *(const bf16x8*)&pa[ii & 1][g][l*8];
      #pragma unroll
      for (int cf = 0; cf < 4; cf++)
        acc[g][cf] = mfma16(ag, bcur[cf], acc[g][cf]);
    }
    __builtin_amdgcn_s_setprio(0);
    if (have_next) *(uint4*)&pa[(ii+1) & 1][w][l*8] = u1;
    __syncthreads();
    #pragma unroll
    for (int cf = 0; cf < 4; cf++) bcur[cf] = bnxt[cf];
  }
  #undef GENP_ALL

  psum += __shfl_xor(psum, 16, 64);
  psum += __shfl_xor(psum, 32, 64);
  if (lq == 0) part_d[(long)(slice*2 + h)*N_NODES + rp] = psum;

  float* pb = part + ((long)(slice*2 + h)*N_NODES)*DHEAD;
  #pragma unroll
  for (int g = 0; g < 4; g++){
    #pragma unroll
    for (int reg = 0; reg < 4; reg++){
      int r = blockbase + g*16 + lq*4 + reg;
      #pragma unroll
      for (int cf = 0; cf < 4; cf++){
        int c = colw + cf*16 + l15;
        pb[(long)r*DHEAD + c] = acc[g][cf][reg];
      }
    }
  }
}

// ---------------- attn combine (d from part_d slices) ----------------
__global__ void attn_combine_kernel(
    const float* __restrict__ part, const float* __restrict__ part_d,
    const float* __restrict__ bias, unsigned short* __restrict__ out,
    int do_elu, int slices)
{
  int h = blockIdx.y;
  int w = threadIdx.x >> 6, l = threadIdx.x & 63;
  int r = blockIdx.x*4 + w;
  float4 s = {0.f,0.f,0.f,0.f};
  float dsum = 0.f;
  for (int sl = 0; sl < slices; ++sl){
    float4 v = *(const float4*)&part[(((long)(sl*2 + h))*N_NODES + r)*DHEAD + l*4];
    s.x += v.x; s.y += v.y; s.z += v.z; s.w += v.w;
    dsum += part_d[(long)(sl*2 + h)*N_NODES + r];
  }
  float invd = 1.0f / fmaxf(dsum, 1e-30f);
  float o0 = s.x*invd, o1 = s.y*invd, o2 = s.z*invd, o3 = s.w*invd;
  o0 = o0 > 0.f ? o0 : 0.2f*o0;  o1 = o1 > 0.f ? o1 : 0.2f*o1;
  o2 = o2 > 0.f ? o2 : 0.2f*o2;  o3 = o3 > 0.f ? o3 : 0.2f*o3;
  float ss = o0*o0 + o1*o1 + o2*o2 + o3*o3;
  #pragma unroll
  for (int o = 32; o > 0; o >>= 1) ss += __shfl_xor(ss, o, 64);
  float invn = 1.0f / fmaxf(sqrtf(ss), 1e-12f);
  const float* bp = bias + h*DHEAD + l*4;
  float v0 = o0*invn + bp[0], v1 = o1*invn + bp[1], v2 = o2*invn + bp[2], v3 = o3*invn + bp[3];
  if (do_elu){
    v0 = v0 > 0.f ? v0 : expm1f(v0); v1 = v1 > 0.f ? v1 : expm1f(v1);
    v2 = v2 > 0.f ? v2 : expm1f(v2); v3 = v3 > 0.f ? v3 : expm1f(v3);
  }
  ushort4 r4;
  r4.x = f2bf(v0); r4.y = f2bf(v1); r4.z = f2bf(v2); r4.w = f2bf(v3);
  *(ushort4*)&out[(long)r*HID + h*DHEAD + l*4] = r4;
}

// ---------------- fallback attn (round-11, self-contained) ------------------------
__global__ void attn_kernel(
    const float* __restrict__ q, const float* __restrict__ k,
    const float* __restrict__ m, const float* __restrict__ d,
    const unsigned char* __restrict__ mb,
    const unsigned short* __restrict__ vT,
    const float* __restrict__ bias,
    unsigned short* __restrict__ out,
    int do_elu)
{
  __shared__ __align__(16) unsigned short pa[2][4][512];
  __shared__ float sred[4][64];
  int h = blockIdx.y;
  q += (long)h*N_NODES; k += (long)h*N_NODES; m += (long)h*N_NODES; d += (long)h*N_NODES;
  vT += (long)h*DHEAD*N_NODES;
  bias += h*DHEAD;
  int col_ofs = h*DHEAD;
  int tid = threadIdx.x;
  int w = tid >> 6, l = tid & 63;
  int l15 = l & 15, lq = l >> 4;
  int blockbase = blockIdx.x*64;
  int rp = blockbase + w*16 + l15;
  float qp = q[rp], mp = m[rp];
  const unsigned char* mrow = mb + (long)rp*MB_ROW;
  int colw = w*64;
  const unsigned short* vbase = vT + (colw + l15)*32 + lq*8;
  f32x4 zero = {0.f,0.f,0.f,0.f};
  f32x4 acc[4][4];
  #pragma unroll
  for (int g = 0; g < 4; g++)
    #pragma unroll
    for (int cf = 0; cf < 4; cf++) acc[g][cf] = zero;
  bf16x8 bcur[4], bnxt[4];
  #pragma unroll
  for (int cf = 0; cf < 4; cf++) bcur[cf] = *(const bf16x8*)(vbase + cf*512);
  const int NT = N_NODES/32;
  for (int it = 0; it < NT; ++it){
    int jt = it*32;
    if (it+1 < NT){
      const unsigned short* vb2 = vbase + (long)(it+1)*(DHEAD*32);
      #pragma unroll
      for (int cf = 0; cf < 4; cf++) bnxt[cf] = *(const bf16x8*)(vb2 + cf*512);
    }
    int jb = jt + lq*8;
    float4 ka = *(const float4*)(k + jb);
    float4 kb4 = *(const float4*)(k + jb + 4);
    unsigned int mb0 = mrow[(jt >> 3) + lq];
    bf16x8 a0;
    float s;
    #define GENP(KV,E) \
      s = qp + (KV); s = s > 0.f ? s : 0.2f*s; \
      a0[E] = (short)(((mb0 >> E) & 1u) ? f2bf(__expf(s - mp)) : (unsigned short)0);
    GENP(ka.x,0) GENP(ka.y,1) GENP(ka.z,2) GENP(ka.w,3)
    GENP(kb4.x,4) GENP(kb4.y,5) GENP(kb4.z,6) GENP(kb4.w,7)
    #undef GENP
    *(bf16x8*)&pa[it & 1][w][l*8] = a0;
    __syncthreads();
    #pragma unroll
    for (int g = 0; g < 4; g++){
      bf16x8 ag = *(const bf16x8*)&pa[it & 1][g][l*8];
      #pragma unroll
      for (int cf = 0; cf < 4; cf++)
        acc[g][cf] = mfma16(ag, bcur[cf], acc[g][cf]);
    }
    #pragma unroll
    for (int cf = 0; cf < 4; cf++) bcur[cf] = bnxt[cf];
  }
  #pragma unroll
  for (int g = 0; g < 4; g++){
    #pragma unroll
    for (int reg = 0; reg < 4; reg++){
      int rb = g*16 + lq*4 + reg;
      float invd = 1.0f / d[blockbase + rb];
      float ss = 0.f;
      #pragma unroll
      for (int cf = 0; cf < 4; cf++){
        float o = acc[g][cf][reg] * invd;
        o = o > 0.f ? o : 0.2f*o;
        acc[g][cf][reg] = o;
        ss += o*o;
      }
      #pragma unroll
      for (int o2 = 1; o2 < 16; o2 <<= 1) ss += __shfl_xor(ss, o2, 64);
      if (l15 == 0) sred[w][rb] = ss;
    }
  }
  __syncthreads();
  #pragma unroll
  for (int g = 0; g < 4; g++){
    #pragma unroll
    for (int reg = 0; reg < 4; reg++){
      int rb = g*16 + lq*4 + reg;
      int r = blockbase + rb;
      float tot = sred[0][rb] + sred[1][rb] + sred[2][rb] + sred[3][rb];
      float invn = 1.0f / fmaxf(sqrtf(tot), 1e-12f);
      #pragma unroll
      for (int cf = 0; cf < 4; cf++){
        int c = colw + cf*16 + l15;
        float o = acc[g][cf][reg]*invn + bias[c];
        if (do_elu) o = o > 0.f ? o : expm1f(o);
        out[(long)r*HID + col_ofs + c] = f2bf(o);
      }
    }
  }
}

// ---------------- gather pairs + tiny linear --> FLOAT32 output ----------------
__global__ void final_kernel(const void* __restrict__ ts,
    const float* __restrict__ tf, const float* __restrict__ tg,
    const float* __restrict__ linW, const float* __restrict__ linb,
    float* __restrict__ out, const int* __restrict__ flags)
{
  int w = threadIdx.x >> 6, l = threadIdx.x & 63;
  int b = blockIdx.x*4 + w;
  int i, j;
  if (flags[1]){ const long long* t64 = (const long long*)ts; i = (int)t64[2*b]; j = (int)t64[2*b+1]; }
  else { const int* t32 = (const int*)ts; i = t32[2*b]; j = t32[2*b+1]; }
  i = i < 0 ? 0 : (i >= N_NODES ? N_NODES-1 : i);
  j = j < 0 ? 0 : (j >= N_NODES ? N_NODES-1 : j);
  float t0 = tf[(long)i*DOUT + l],       t1 = tf[(long)i*DOUT + 64 + l];
  float g0 = tg[(long)j*DOUT + l],       g1 = tg[(long)j*DOUT + 64 + l];
  float p0 = t0*linW[2*l]   + t1*linW[2*(64+l)]   + g0*linW[2*(128+l)]   + g1*linW[2*(192+l)];
  float p1 = t0*linW[2*l+1] + t1*linW[2*(64+l)+1] + g0*linW[2*(128+l)+1] + g1*linW[2*(192+l)+1];
  #pragma unroll
  for (int o = 32; o > 0; o >>= 1){ p0 += __shfl_xor(p0, o, 64); p1 += __shfl_xor(p1, o, 64); }
  if (l == 0){
    out[2*b]   = p0 + linb[0];
    out[2*b+1] = p1 + linb[1];
  }
}

extern "C" void kernel_launch(void* const* d_in, const int* in_sizes, int n_in,
                              void* d_out, int out_size, void* d_ws, size_t ws_size,
                              hipStream_t stream){
  (void)in_sizes; (void)n_in; (void)out_size;
  const void* x    = d_in[0];
  const int*  adj  = (const int*)d_in[1];
  const void* ts   = d_in[2];
  const void* W1   = d_in[3];  const void* a1 = d_in[4];  const void* b1 = d_in[5];
  const void* W2   = d_in[6];  const void* a2 = d_in[7];  const void* b2 = d_in[8];
  const void* tf1W = d_in[9];  const void* tf1b = d_in[10];
  const void* tf2W = d_in[11]; const void* tf2b = d_in[12];
  const void* tg1W = d_in[13]; const void* tg1b = d_in[14];
  const void* tg2W = d_in[15]; const void* tg2b = d_in[16];
  const void* linW = d_in[17]; const void* linb = d_in[18];

  char* base = (char*)d_ws; size_t off = 0;
  auto alloc = [&](size_t bytes)->void*{
    void* r = base + off; off = (off + bytes + 255) & ~(size_t)255; return r;
  };
  int* flags                 = (int*)alloc(16);
  float* kmx                 = (float*)alloc(16);
  unsigned long long* bm     = (unsigned long long*)alloc((size_t)MWORDS*8);
  unsigned short* x_bf       = (unsigned short*)alloc((size_t)N_NODES*DIN*2);
  unsigned short* W1T        = (unsigned short*)alloc((size_t)2*DHEAD*DIN*2);
  unsigned short* W2T        = (unsigned short*)alloc((size_t)2*DHEAD*HID*2);
  unsigned short* mlp1WT     = (unsigned short*)alloc((size_t)2*HID*HID*2);
  unsigned short* mlp2WT     = (unsigned short*)alloc((size_t)2*HID*DOUT*2);
  float* smallf              = (float*)alloc(10*1024*4);
  float* v_f32           = (float*)alloc((size_t)2*N_NODES*DHEAD*4);
  unsigned short* vT_bf  = (unsigned short*)alloc((size_t)2*DHEAD*N_NODES*2);
  float* qv = (float*)alloc((size_t)2*N_NODES*4);
  float* kv = (float*)alloc((size_t)2*N_NODES*4);
  float* mv = (float*)alloc((size_t)2*N_NODES*4);
  float* dv = (float*)alloc((size_t)2*N_NODES*4);
  unsigned short* h_bf     = (unsigned short*)alloc((size_t)N_NODES*HID*2);
  unsigned short* embed_bf = (unsigned short*)alloc((size_t)N_NODES*HID*2);
  unsigned short* mid2     = (unsigned short*)alloc((size_t)2*N_NODES*HID*2);
  float* tfg = (float*)alloc((size_t)2*N_NODES*DOUT*4);
  size_t base_need = off;
  int ws_ok = (ws_size >= base_need) ? 1 : 0;

  // param views into smallf
  float* a1f  = smallf + 0*1024;
  float* b1f  = smallf + 1*1024;
  float* a2f  = smallf + 2*1024;
  float* b2f  = smallf + 3*1024;
  float* tf1bf = smallf + 4*1024;
  float* tf2bf = smallf + 5*1024;
  float* linWf = smallf + 8*1024;
  float* linbf = smallf + 9*1024;

  // j-split ladder: 4 preferred (8 showed no gain, 2x partial traffic)
  size_t per_slice = (size_t)2*N_NODES*DHEAD*4 + (size_t)2*N_NODES*4;
  int slices = 0;
  if      (ws_size >= base_need + 4*per_slice + 1024) slices = 4;
  else if (ws_size >= base_need + 2*per_slice + 1024) slices = 2;
  else if (ws_size >= base_need + 1*per_slice + 1024) slices = 1;
  float* part   = (slices > 0) ? (float*)alloc((size_t)slices*2*N_NODES*DHEAD*4) : nullptr;
  float* part_d = (slices > 0) ? (float*)alloc((size_t)slices*2*N_NODES*4) : nullptr;

  detect_kernel<<<1, 256, 0, stream>>>((const unsigned int*)x, (const unsigned int*)ts, flags);

  if (ws_ok){
    conv_bf16_kernel<<<(N_NODES*DIN)/256, 256, 0, stream>>>(x, x_bf, N_NODES*DIN, flags);
    conv_tr6_kernel<<<4608, 256, 0, stream>>>(W1, W2, tf1W, tg1W, tf2W, tg2W,
        W1T, W2T, mlp1WT, mlp1WT + (size_t)HID*HID, mlp2WT, mlp2WT + (size_t)HID*DOUT, flags);
    conv_small_kernel<<<40, 256, 0, stream>>>(a1, b1, a2, b2, tf1b, tf2b, tg1b, tg2b,
                                              linW, linb, smallf, flags);
    bitmask_kernel<<<2048, 256, 0, stream>>>(adj, bm);

    const unsigned char* mbytes = (const unsigned char*)bm;

    // ---- layer 1 ----
    gemm4_kernel<<<dim3(N_NODES/64, 4, 2), 256, 0, stream>>>(
        x_bf, 0, W1T, (long)DHEAD*DIN, DIN, DHEAD, nullptr, 0, 1.0f,
        v_f32, DHEAD, (long)N_NODES*DHEAD, nullptr, 0, 0,
        vT_bf, DHEAD, (long)DHEAD*N_NODES);
    qk_kernel<<<dim3(N_NODES/4, 2), 256, 0, stream>>>(v_f32, a1f, qv, kv);
    if (slices > 0){
      kmax_kernel<<<dim3(1, 2), 256, 0, stream>>>(kv, kmx);
      attn_part_kernel<<<(N_NODES/64)*2*slices, 256, 0, stream>>>(
          qv, kv, kmx, mbytes, vT_bf, part, part_d, (N_NODES/32)/slices, slices);
      attn_combine_kernel<<<dim3(N_NODES/4, 2), 256, 0, stream>>>(part, part_d, b1f, h_bf, 1, slices);
    } else {
      rowstat_kernel<<<dim3(N_NODES, 2), 256, 0, stream>>>(qv, kv, bm, mv, dv);
      attn_kernel<<<dim3(N_NODES/64, 2), 256, 0, stream>>>(qv, kv, mv, dv, mbytes, vT_bf, b1f, h_bf, 1);
    }

    // ---- layer 2 ----
    gemm4_kernel<<<dim3(N_NODES/64, 4, 2), 256, 0, stream>>>(
        h_bf, 0, W2T, (long)DHEAD*HID, HID, DHEAD, nullptr, 0, 1.0f,
        v_f32, DHEAD, (long)N_NODES*DHEAD, nullptr, 0, 0,
        vT_bf, DHEAD, (long)DHEAD*N_NODES);
    qk_kernel<<<dim3(N_NODES/4, 2), 256, 0, stream>>>(v_f32, a2f, qv, kv);
    if (slices > 0){
      kmax_kernel<<<dim3(1, 2), 256, 0, stream>>>(kv, kmx + 2);
      attn_part_kernel<<<(N_NODES/64)*2*slices, 256, 0, stream>>>(
          qv, kv, kmx + 2, mbytes, vT_bf, part, part_d, (N_NODES/32)/slices, slices);
      attn_combine_kernel<<<dim3(N_NODES/4, 2), 256, 0, stream>>>(part, part_d, b2f, embed_bf, 0, slices);
    } else {
      rowstat_kernel<<<dim3(N_NODES, 2), 256, 0, stream>>>(qv, kv, bm, mv, dv);
      attn_kernel<<<dim3(N_NODES/64, 2), 256, 0, stream>>>(qv, kv, mv, dv, mbytes, vT_bf, b2f, embed_bf, 0);
    }

    // ---- MLP heads: tf & tg batched via z ----
    gemm8_kernel<<<dim3(N_NODES/64, 4, 2), 256, 0, stream>>>(
        embed_bf, 0, mlp1WT, (long)HID*HID, HID, HID, tf1bf, 2048, 0.01f,
        nullptr, 0, 0, mid2, HID, (long)N_NODES*HID, nullptr, 0, 0);
    gemm4_kernel<<<dim3(N_NODES/64, 2, 2), 256, 0, stream>>>(
        mid2, (long)N_NODES*HID, mlp2WT, (long)HID*DOUT, HID, DOUT, tf2bf, 2048, 0.01f,
        tfg, DOUT, (long)N_NODES*DOUT, nullptr, 0, 0, nullptr, 0, 0);

    // ---- gather + linear (float32 output) ----
    final_kernel<<<NPAIRS/4, 256, 0, stream>>>(ts, tfg, tfg + (size_t)N_NODES*DOUT,
                                               linWf, linbf, (float*)d_out, flags);
  }
}

// Round 21
// 395.158 us; speedup vs baseline: 1.7163x; 1.0058x over previous
//
#include <hip/hip_runtime.h>
#include <math.h>

#define N_NODES 6144
#define DIN 512
#define DHEAD 256
#define HID 512
#define DOUT 128
#define NPAIRS 16384
#define MW_ROW 96           // mask uint64 words per row
#define MB_ROW 768          // mask bytes per row
#define MWORDS (N_NODES*MW_ROW)
#define LOG2E 1.44269504088896341f

typedef __attribute__((ext_vector_type(8))) short bf16x8;
typedef __attribute__((ext_vector_type(4))) float f32x4;

static __device__ __forceinline__ float bf2f(unsigned short u){
  unsigned int x = ((unsigned int)u) << 16;
  return __builtin_bit_cast(float, x);
}
static __device__ __forceinline__ unsigned short f2bf(float f){
  unsigned int x = __builtin_bit_cast(unsigned int, f);
  x += 0x7FFFu + ((x >> 16) & 1u);   // RNE
  return (unsigned short)(x >> 16);
}
static __device__ __forceinline__ f32x4 mfma16(bf16x8 a, bf16x8 b, f32x4 c){
  return __builtin_amdgcn_mfma_f32_16x16x32_bf16(a, b, c, 0, 0, 0);
}
static __device__ __forceinline__ float fexp2(float x){
  return __builtin_amdgcn_exp2f(x);   // v_exp_f32 (q,k pre-scaled by log2e)
}

// ---------------- dtype detection (device-proven: flags={1,0}) ----------------
__global__ void detect_kernel(const unsigned int* __restrict__ xw,
                              const unsigned int* __restrict__ tsw,
                              int* __restrict__ flags){
  __shared__ int s_cnt; __shared__ unsigned int s_or;
  if (threadIdx.x == 0){ s_cnt = 0; s_or = 0u; }
  __syncthreads();
  int cnt = 0;
  for (int i = threadIdx.x; i < 4096; i += 256){
    unsigned int e = (xw[i] >> 7) & 0xFFu;
    cnt += (e > 100u && e < 150u) ? 1 : 0;
  }
  unsigned int ov = 0u;
  for (int i = threadIdx.x; i < 2048; i += 256) ov |= tsw[2*i + 1];
  atomicAdd(&s_cnt, cnt);
  atomicOr(&s_or, ov);
  __syncthreads();
  if (threadIdx.x == 0){
    flags[0] = (s_cnt < 2048) ? 1 : 0;
    flags[1] = (s_or == 0u) ? 1 : 0;
  }
}

// ---------------- conversions ----------------
__global__ void conv_bf16_kernel(const void* __restrict__ src, unsigned short* __restrict__ dst,
                                 int n, const int* __restrict__ flags){
  int i = blockIdx.x*256 + threadIdx.x;
  if (i >= n) return;
  dst[i] = flags[0] ? f2bf(((const float*)src)[i]) : ((const unsigned short*)src)[i];
}

// all 10 small f32 params in one launch; dst slots of 1024 floats each.
// slots 0 (a1) and 2 (a2) are pre-scaled by log2(e): q,k become log2-domain so
// attention uses exp2 directly (lrelu is positively homogeneous -> same softmax).
__global__ void conv_small_kernel(const void* s0, const void* s1, const void* s2,
    const void* s3, const void* s4, const void* s5, const void* s6,
    const void* s7, const void* s8, const void* s9,
    float* __restrict__ dst, const int* __restrict__ flags){
  static const int lens[10] = {1024,512,1024,512,512,128,512,128,512,2};
  int slot = blockIdx.x >> 2;
  int idx = (blockIdx.x & 3)*256 + threadIdx.x;
  const void* srcs[10] = {s0,s1,s2,s3,s4,s5,s6,s7,s8,s9};
  if (idx < lens[slot]){
    const void* s = srcs[slot];
    float v = flags[0] ? ((const float*)s)[idx] : bf2f(((const unsigned short*)s)[idx]);
    if (slot == 0 || slot == 2) v *= LOG2E;
    dst[slot*1024 + idx] = v;
  }
}

// all 6 weight transposes (K=512 each) in one launch; strip-blocked [K/32][Nn][32]
__global__ void conv_tr6_kernel(const void* s0, const void* s1, const void* s2,
    const void* s3, const void* s4, const void* s5,
    unsigned short* d0, unsigned short* d1, unsigned short* d2,
    unsigned short* d3, unsigned short* d4, unsigned short* d5,
    const int* __restrict__ flags){
  static const int bstart[6] = {0,1024,2048,3072,4096,4352};
  static const int NnT[6] = {256,256,512,512,128,128};
  int b = blockIdx.x;
  int e = 0;
  #pragma unroll
  for (int t = 1; t < 6; t++) if (b >= bstart[t]) e = t;
  const void* srcs[6] = {s0,s1,s2,s3,s4,s5};
  unsigned short* dsts[6] = {d0,d1,d2,d3,d4,d5};
  int Nn = NnT[e];
  int per = 512*Nn;
  long li = (long)(b - bstart[e])*256 + threadIdx.x;
  int bb = (int)(li / per); int i = (int)(li % per);
  int k = i / Nn, n = i % Nn;
  const void* s = srcs[e];
  unsigned short us = flags[0] ? f2bf(((const float*)s)[(long)bb*per + i])
                               : ((const unsigned short*)s)[(long)bb*per + i];
  dsts[e][(long)bb*per + (long)(k >> 5)*Nn*32 + (long)n*32 + (k & 31)] = us;
}

// ---------------- adjacency bitmask ----------------
__global__ void bitmask_kernel(const int* __restrict__ adj, unsigned long long* __restrict__ bm){
  int gid = blockIdx.x*blockDim.x + threadIdx.x;
  int l = gid & 63;
  int wv = gid >> 6;
  int nw = (gridDim.x*blockDim.x) >> 6;
  for (int word = wv; word < MWORDS; word += nw){
    int v = adj[(long)word*64 + l];
    unsigned long long mask = __ballot(v > 0);
    if (l == 0) bm[word] = mask;
  }
}

// ---------------- dense GEMM (strip-blocked B; batched A/B/bias/outB) ----------------
#define GEMM_BODY(CF) \
  int bb = blockIdx.z; \
  A += (long)bb*a_bstride; \
  BT += (long)bb*bt_bstride; \
  const float* bias_p = bias ? (bias + (long)bb*bias_bstride) : (const float*)0; \
  int w = threadIdx.x >> 6, l = threadIdx.x & 63; \
  int l15 = l & 15, lq = l >> 4; \
  int arow = blockIdx.x*64 + w*16 + l15; \
  int colbase = blockIdx.y * (CF*16); \
  f32x4 zero = {0.f,0.f,0.f,0.f}; \
  f32x4 acc[CF]; \
  _Pragma("unroll") \
  for (int i = 0; i < CF; i++) acc[i] = zero; \
  for (int kt = 0; kt < K; kt += 32){ \
    bf16x8 a = *(const bf16x8*)(A + (long)arow*K + kt + lq*8); \
    const unsigned short* bp = BT + (long)(kt >> 5)*bn*32 + lq*8; \
    _Pragma("unroll") \
    for (int cf = 0; cf < CF; cf++){ \
      bf16x8 b = *(const bf16x8*)(bp + (colbase + cf*16 + l15)*32); \
      acc[cf] = mfma16(a, b, acc[cf]); \
    } \
  } \
  int orow0 = blockIdx.x*64 + w*16 + lq*4; \
  _Pragma("unroll") \
  for (int reg = 0; reg < 4; reg++){ \
    int r = orow0 + reg; \
    _Pragma("unroll") \
    for (int cf = 0; cf < CF; cf++){ \
      int c = colbase + cf*16 + l15; \
      float v = acc[cf][reg]; \
      if (bias_p) v += bias_p[c]; \
      v = v > 0.f ? v : slope * v; \
      if (outF) outF[(long)bb*outF_bstride + (long)r*ldF + c] = v; \
      if (outB) outB[(long)bb*outB_bstride + (long)r*ldB + c] = f2bf(v); \
      if (outT) outT[(long)bb*outT_bstride + (long)(r >> 5)*ldT*32 + (long)c*32 + (r & 31)] = f2bf(v); \
    } \
  }

__global__ void gemm8_kernel(
    const unsigned short* __restrict__ A, long a_bstride,
    const unsigned short* __restrict__ BT, long bt_bstride,
    int K, int bn, const float* __restrict__ bias, long bias_bstride, float slope,
    float* __restrict__ outF, int ldF, long outF_bstride,
    unsigned short* __restrict__ outB, int ldB, long outB_bstride,
    unsigned short* __restrict__ outT, int ldT, long outT_bstride)
{ GEMM_BODY(8) }

__global__ void gemm4_kernel(
    const unsigned short* __restrict__ A, long a_bstride,
    const unsigned short* __restrict__ BT, long bt_bstride,
    int K, int bn, const float* __restrict__ bias, long bias_bstride, float slope,
    float* __restrict__ outF, int ldF, long outF_bstride,
    unsigned short* __restrict__ outB, int ldB, long outB_bstride,
    unsigned short* __restrict__ outT, int ldT, long outT_bstride)
{ GEMM_BODY(4) }

// ---------------- q,k GEMV (lean; no atomics) ----------------
__global__ void qk_kernel(const float* __restrict__ v,
    const float* __restrict__ avec, float* __restrict__ q, float* __restrict__ k){
  int h = blockIdx.y;
  v += (long)h*N_NODES*DHEAD; avec += h*2*DHEAD; q += (long)h*N_NODES; k += (long)h*N_NODES;
  int w = threadIdx.x >> 6, l = threadIdx.x & 63;
  int row = blockIdx.x*4 + w;
  float sq = 0.f, sk = 0.f;
  #pragma unroll
  for (int t = 0; t < 4; t++){
    int c = l + t*64;
    float vv = v[(long)row*DHEAD + c];
    sq += vv * avec[c];
    sk += vv * avec[DHEAD + c];
  }
  #pragma unroll
  for (int o = 32; o > 0; o >>= 1){ sq += __shfl_xor(sq, o, 64); sk += __shfl_xor(sk, o, 64); }
  if (l == 0){ q[row] = sq; k[row] = sk; }
}

// ---------------- per-head kmax: one block per head, deterministic ----------------
__global__ void kmax_kernel(const float* __restrict__ k, float* __restrict__ kmx){
  int h = blockIdx.y;
  k += (long)h*N_NODES;
  int t = threadIdx.x;
  float mx = -INFINITY;
  #pragma unroll
  for (int it = 0; it < 24; it++) mx = fmaxf(mx, k[t + it*256]);
  #pragma unroll
  for (int o = 32; o > 0; o >>= 1) mx = fmaxf(mx, __shfl_xor(mx, o, 64));
  __shared__ float red[4];
  if ((t & 63) == 0) red[t >> 6] = mx;
  __syncthreads();
  if (t == 0) kmx[h] = fmaxf(fmaxf(red[0], red[1]), fmaxf(red[2], red[3]));
}

// ---------------- full rowstat (fallback path only; log2-domain scores) ------------
__global__ void rowstat_kernel(const float* __restrict__ q,
    const float* __restrict__ k, const unsigned long long* __restrict__ bm,
    float* __restrict__ m, float* __restrict__ d){
  int h = blockIdx.y;
  q += (long)h*N_NODES; k += (long)h*N_NODES; m += (long)h*N_NODES; d += (long)h*N_NODES;
  int i = blockIdx.x;
  int t = threadIdx.x;
  float qi = q[i];
  float sv[24];
  float smax = -INFINITY;
  #pragma unroll
  for (int it = 0; it < 24; it++){
    int j = t + it*256;
    unsigned long long wm = bm[(long)i*MW_ROW + (j >> 6)];
    float s = qi + k[j];
    s = s > 0.f ? s : 0.2f*s;
    s = ((wm >> (j & 63)) & 1ULL) ? s : -INFINITY;
    sv[it] = s;
    smax = fmaxf(smax, s);
  }
  __shared__ float red[4];
  __shared__ float red2[4];
  #pragma unroll
  for (int o = 32; o > 0; o >>= 1) smax = fmaxf(smax, __shfl_xor(smax, o, 64));
  if ((t & 63) == 0) red[t >> 6] = smax;
  __syncthreads();
  float bmax = fmaxf(fmaxf(red[0], red[1]), fmaxf(red[2], red[3]));
  float ssum = 0.f;
  #pragma unroll
  for (int it = 0; it < 24; it++) ssum += fexp2(sv[it] - bmax);
  #pragma unroll
  for (int o = 32; o > 0; o >>= 1) ssum += __shfl_xor(ssum, o, 64);
  if ((t & 63) == 0) red2[t >> 6] = ssum;
  __syncthreads();
  if (t == 0){
    if (bmax == -INFINITY){ m[i] = 0.f; d[i] = 1.f; }
    else { m[i] = bmax; d[i] = red2[0]+red2[1]+red2[2]+red2[3]; }
  }
}

// ---------------- attn partial: m' = lrelu(q+kmax); exp2 domain; fused d -----------
__global__ void attn_part_kernel(
    const float* __restrict__ q, const float* __restrict__ k,
    const float* __restrict__ kmx,
    const unsigned char* __restrict__ mb,
    const unsigned short* __restrict__ vT,
    float* __restrict__ part,                // [slice][head][N][DHEAD] f32
    float* __restrict__ part_d,              // [slice][head][N] f32 row-sum partials
    int nstrips, int slices)
{
  __shared__ __align__(16) unsigned short pa[2][4][512];
  int npair = 2*slices;
  int id = blockIdx.x;
  int pair = id % npair;
  int rowblk = id / npair;
  int h = pair % 2;
  int slice = pair / 2;

  q += (long)h*N_NODES; k += (long)h*N_NODES;
  vT += (long)h*DHEAD*N_NODES;

  int tid = threadIdx.x;
  int w = tid >> 6, l = tid & 63;
  int l15 = l & 15, lq = l >> 4;
  int blockbase = rowblk*64;

  int rp = blockbase + w*16 + l15;
  float qp = q[rp];
  float km = kmx[h];
  float mp = qp + km;  mp = mp > 0.f ? mp : 0.2f*mp;   // upper bound of row scores
  const unsigned char* mrow = mb + (long)rp*MB_ROW;

  int colw = w*64;
  const unsigned short* vbase = vT + (colw + l15)*32 + lq*8;
  int it0 = slice * nstrips;

  f32x4 zero = {0.f,0.f,0.f,0.f};
  f32x4 acc[4][4];
  #pragma unroll
  for (int g = 0; g < 4; g++)
    #pragma unroll
    for (int cf = 0; cf < 4; cf++) acc[g][cf] = zero;

  float psum = 0.f;

  bf16x8 bcur[4], bnxt[4];
  #pragma unroll
  for (int cf = 0; cf < 4; cf++)
    bcur[cf] = *(const bf16x8*)(vbase + (long)it0*(DHEAD*32) + cf*512);

  #define GENP_ALL(JT, DSTU) do { \
    int jb_ = (JT) + lq*8; \
    float4 ka_ = *(const float4*)(k + jb_); \
    float4 kb_ = *(const float4*)(k + jb_ + 4); \
    unsigned int mb_ = mrow[((JT) >> 3) + lq]; \
    float s_, e0_, e1_; \
    s_ = qp + ka_.x; s_ = s_>0.f? s_:0.2f*s_; e0_ = ((mb_>>0)&1u)? fexp2(s_-mp):0.f; \
    s_ = qp + ka_.y; s_ = s_>0.f? s_:0.2f*s_; e1_ = ((mb_>>1)&1u)? fexp2(s_-mp):0.f; \
    (DSTU).x = ((unsigned int)f2bf(e1_)<<16) | f2bf(e0_); \
    psum += e0_ + e1_; \
    s_ = qp + ka_.z; s_ = s_>0.f? s_:0.2f*s_; e0_ = ((mb_>>2)&1u)? fexp2(s_-mp):0.f; \
    s_ = qp + ka_.w; s_ = s_>0.f? s_:0.2f*s_; e1_ = ((mb_>>3)&1u)? fexp2(s_-mp):0.f; \
    (DSTU).y = ((unsigned int)f2bf(e1_)<<16) | f2bf(e0_); \
    psum += e0_ + e1_; \
    s_ = qp + kb_.x; s_ = s_>0.f? s_:0.2f*s_; e0_ = ((mb_>>4)&1u)? fexp2(s_-mp):0.f; \
    s_ = qp + kb_.y; s_ = s_>0.f? s_:0.2f*s_; e1_ = ((mb_>>5)&1u)? fexp2(s_-mp):0.f; \
    (DSTU).z = ((unsigned int)f2bf(e1_)<<16) | f2bf(e0_); \
    psum += e0_ + e1_; \
    s_ = qp + kb_.z; s_ = s_>0.f? s_:0.2f*s_; e0_ = ((mb_>>6)&1u)? fexp2(s_-mp):0.f; \
    s_ = qp + kb_.w; s_ = s_>0.f? s_:0.2f*s_; e1_ = ((mb_>>7)&1u)? fexp2(s_-mp):0.f; \
    (DSTU).w = ((unsigned int)f2bf(e1_)<<16) | f2bf(e0_); \
    psum += e0_ + e1_; \
  } while(0)

  {
    uint4 u0;
    GENP_ALL(it0*32, u0);
    *(uint4*)&pa[0][w][l*8] = u0;
  }
  __syncthreads();

  for (int ii = 0; ii < nstrips; ++ii){
    int it = it0 + ii;
    bool have_next = (ii+1 < nstrips);
    if (have_next){
      const unsigned short* vb2 = vbase + (long)(it+1)*(DHEAD*32);
      #pragma unroll
      for (int cf = 0; cf < 4; cf++) bnxt[cf] = *(const bf16x8*)(vb2 + cf*512);
    }
    uint4 u1;
    if (have_next) GENP_ALL((it+1)*32, u1);
    #pragma unroll
    for (int g = 0; g < 4; g++){
      bf16x8 ag = *(const bf16x8*)&pa[ii & 1][g][l*8];
      #pragma unroll
      for (int cf = 0; cf < 4; cf++)
        acc[g][cf] = mfma16(ag, bcur[cf], acc[g][cf]);
    }
    if (have_next) *(uint4*)&pa[(ii+1) & 1][w][l*8] = u1;
    __syncthreads();
    #pragma unroll
    for (int cf = 0; cf < 4; cf++) bcur[cf] = bnxt[cf];
  }
  #undef GENP_ALL

  psum += __shfl_xor(psum, 16, 64);
  psum += __shfl_xor(psum, 32, 64);
  if (lq == 0) part_d[(long)(slice*2 + h)*N_NODES + rp] = psum;

  float* pb = part + ((long)(slice*2 + h)*N_NODES)*DHEAD;
  #pragma unroll
  for (int g = 0; g < 4; g++){
    #pragma unroll
    for (int reg = 0; reg < 4; reg++){
      int r = blockbase + g*16 + lq*4 + reg;
      #pragma unroll
      for (int cf = 0; cf < 4; cf++){
        int c = colw + cf*16 + l15;
        pb[(long)r*DHEAD + c] = acc[g][cf][reg];
      }
    }
  }
}

// ---------------- attn combine (d from part_d slices) ----------------
__global__ void attn_combine_kernel(
    const float* __restrict__ part, const float* __restrict__ part_d,
    const float* __restrict__ bias, unsigned short* __restrict__ out,
    int do_elu, int slices)
{
  int h = blockIdx.y;
  int w = threadIdx.x >> 6, l = threadIdx.x & 63;
  int r = blockIdx.x*4 + w;
  float4 s = {0.f,0.f,0.f,0.f};
  float dsum = 0.f;
  for (int sl = 0; sl < slices; ++sl){
    float4 v = *(const float4*)&part[(((long)(sl*2 + h))*N_NODES + r)*DHEAD + l*4];
    s.x += v.x; s.y += v.y; s.z += v.z; s.w += v.w;
    dsum += part_d[(long)(sl*2 + h)*N_NODES + r];
  }
  float invd = 1.0f / fmaxf(dsum, 1e-30f);
  float o0 = s.x*invd, o1 = s.y*invd, o2 = s.z*invd, o3 = s.w*invd;
  o0 = o0 > 0.f ? o0 : 0.2f*o0;  o1 = o1 > 0.f ? o1 : 0.2f*o1;
  o2 = o2 > 0.f ? o2 : 0.2f*o2;  o3 = o3 > 0.f ? o3 : 0.2f*o3;
  float ss = o0*o0 + o1*o1 + o2*o2 + o3*o3;
  #pragma unroll
  for (int o = 32; o > 0; o >>= 1) ss += __shfl_xor(ss, o, 64);
  float invn = 1.0f / fmaxf(sqrtf(ss), 1e-12f);
  const float* bp = bias + h*DHEAD + l*4;
  float v0 = o0*invn + bp[0], v1 = o1*invn + bp[1], v2 = o2*invn + bp[2], v3 = o3*invn + bp[3];
  if (do_elu){
    v0 = v0 > 0.f ? v0 : expm1f(v0); v1 = v1 > 0.f ? v1 : expm1f(v1);
    v2 = v2 > 0.f ? v2 : expm1f(v2); v3 = v3 > 0.f ? v3 : expm1f(v3);
  }
  ushort4 r4;
  r4.x = f2bf(v0); r4.y = f2bf(v1); r4.z = f2bf(v2); r4.w = f2bf(v3);
  *(ushort4*)&out[(long)r*HID + h*DHEAD + l*4] = r4;
}

// ---------------- fallback attn (log2-domain scores; fallback path only) -----------
__global__ void attn_kernel(
    const float* __restrict__ q, const float* __restrict__ k,
    const float* __restrict__ m, const float* __restrict__ d,
    const unsigned char* __restrict__ mb,
    const unsigned short* __restrict__ vT,
    const float* __restrict__ bias,
    unsigned short* __restrict__ out,
    int do_elu)
{
  __shared__ __align__(16) unsigned short pa[2][4][512];
  __shared__ float sred[4][64];
  int h = blockIdx.y;
  q += (long)h*N_NODES; k += (long)h*N_NODES; m += (long)h*N_NODES; d += (long)h*N_NODES;
  vT += (long)h*DHEAD*N_NODES;
  bias += h*DHEAD;
  int col_ofs = h*DHEAD;
  int tid = threadIdx.x;
  int w = tid >> 6, l = tid & 63;
  int l15 = l & 15, lq = l >> 4;
  int blockbase = blockIdx.x*64;
  int rp = blockbase + w*16 + l15;
  float qp = q[rp], mp = m[rp];
  const unsigned char* mrow = mb + (long)rp*MB_ROW;
  int colw = w*64;
  const unsigned short* vbase = vT + (colw + l15)*32 + lq*8;
  f32x4 zero = {0.f,0.f,0.f,0.f};
  f32x4 acc[4][4];
  #pragma unroll
  for (int g = 0; g < 4; g++)
    #pragma unroll
    for (int cf = 0; cf < 4; cf++) acc[g][cf] = zero;
  bf16x8 bcur[4], bnxt[4];
  #pragma unroll
  for (int cf = 0; cf < 4; cf++) bcur[cf] = *(const bf16x8*)(vbase + cf*512);
  const int NT = N_NODES/32;
  for (int it = 0; it < NT; ++it){
    int jt = it*32;
    if (it+1 < NT){
      const unsigned short* vb2 = vbase + (long)(it+1)*(DHEAD*32);
      #pragma unroll
      for (int cf = 0; cf < 4; cf++) bnxt[cf] = *(const bf16x8*)(vb2 + cf*512);
    }
    int jb = jt + lq*8;
    float4 ka = *(const float4*)(k + jb);
    float4 kb4 = *(const float4*)(k + jb + 4);
    unsigned int mb0 = mrow[(jt >> 3) + lq];
    bf16x8 a0;
    float s;
    #define GENP(KV,E) \
      s = qp + (KV); s = s > 0.f ? s : 0.2f*s; \
      a0[E] = (short)(((mb0 >> E) & 1u) ? f2bf(fexp2(s - mp)) : (unsigned short)0);
    GENP(ka.x,0) GENP(ka.y,1) GENP(ka.z,2) GENP(ka.w,3)
    GENP(kb4.x,4) GENP(kb4.y,5) GENP(kb4.z,6) GENP(kb4.w,7)
    #undef GENP
    *(bf16x8*)&pa[it & 1][w][l*8] = a0;
    __syncthreads();
    #pragma unroll
    for (int g = 0; g < 4; g++){
      bf16x8 ag = *(const bf16x8*)&pa[it & 1][g][l*8];
      #pragma unroll
      for (int cf = 0; cf < 4; cf++)
        acc[g][cf] = mfma16(ag, bcur[cf], acc[g][cf]);
    }
    #pragma unroll
    for (int cf = 0; cf < 4; cf++) bcur[cf] = bnxt[cf];
  }
  #pragma unroll
  for (int g = 0; g < 4; g++){
    #pragma unroll
    for (int reg = 0; reg < 4; reg++){
      int rb = g*16 + lq*4 + reg;
      float invd = 1.0f / d[blockbase + rb];
      float ss = 0.f;
      #pragma unroll
      for (int cf = 0; cf < 4; cf++){
        float o = acc[g][cf][reg] * invd;
        o = o > 0.f ? o : 0.2f*o;
        acc[g][cf][reg] = o;
        ss += o*o;
      }
      #pragma unroll
      for (int o2 = 1; o2 < 16; o2 <<= 1) ss += __shfl_xor(ss, o2, 64);
      if (l15 == 0) sred[w][rb] = ss;
    }
  }
  __syncthreads();
  #pragma unroll
  for (int g = 0; g < 4; g++){
    #pragma unroll
    for (int reg = 0; reg < 4; reg++){
      int rb = g*16 + lq*4 + reg;
      int r = blockbase + rb;
      float tot = sred[0][rb] + sred[1][rb] + sred[2][rb] + sred[3][rb];
      float invn = 1.0f / fmaxf(sqrtf(tot), 1e-12f);
      #pragma unroll
      for (int cf = 0; cf < 4; cf++){
        int c = colw + cf*16 + l15;
        float o = acc[g][cf][reg]*invn + bias[c];
        if (do_elu) o = o > 0.f ? o : expm1f(o);
        out[(long)r*HID + col_ofs + c] = f2bf(o);
      }
    }
  }
}

// ---------------- gather pairs + tiny linear --> FLOAT32 output ----------------
__global__ void final_kernel(const void* __restrict__ ts,
    const float* __restrict__ tf, const float* __restrict__ tg,
    const float* __restrict__ linW, const float* __restrict__ linb,
    float* __restrict__ out, const int* __restrict__ flags)
{
  int w = threadIdx.x >> 6, l = threadIdx.x & 63;
  int b = blockIdx.x*4 + w;
  int i, j;
  if (flags[1]){ const long long* t64 = (const long long*)ts; i = (int)t64[2*b]; j = (int)t64[2*b+1]; }
  else { const int* t32 = (const int*)ts; i = t32[2*b]; j = t32[2*b+1]; }
  i = i < 0 ? 0 : (i >= N_NODES ? N_NODES-1 : i);
  j = j < 0 ? 0 : (j >= N_NODES ? N_NODES-1 : j);
  float t0 = tf[(long)i*DOUT + l],       t1 = tf[(long)i*DOUT + 64 + l];
  float g0 = tg[(long)j*DOUT + l],       g1 = tg[(long)j*DOUT + 64 + l];
  float p0 = t0*linW[2*l]   + t1*linW[2*(64+l)]   + g0*linW[2*(128+l)]   + g1*linW[2*(192+l)];
  float p1 = t0*linW[2*l+1] + t1*linW[2*(64+l)+1] + g0*linW[2*(128+l)+1] + g1*linW[2*(192+l)+1];
  #pragma unroll
  for (int o = 32; o > 0; o >>= 1){ p0 += __shfl_xor(p0, o, 64); p1 += __shfl_xor(p1, o, 64); }
  if (l == 0){
    out[2*b]   = p0 + linb[0];
    out[2*b+1] = p1 + linb[1];
  }
}

extern "C" void kernel_launch(void* const* d_in, const int* in_sizes, int n_in,
                              void* d_out, int out_size, void* d_ws, size_t ws_size,
                              hipStream_t stream){
  (void)in_sizes; (void)n_in; (void)out_size;
  const void* x    = d_in[0];
  const int*  adj  = (const int*)d_in[1];
  const void* ts   = d_in[2];
  const void* W1   = d_in[3];  const void* a1 = d_in[4];  const void* b1 = d_in[5];
  const void* W2   = d_in[6];  const void* a2 = d_in[7];  const void* b2 = d_in[8];
  const void* tf1W = d_in[9];  const void* tf1b = d_in[10];
  const void* tf2W = d_in[11]; const void* tf2b = d_in[12];
  const void* tg1W = d_in[13]; const void* tg1b = d_in[14];
  const void* tg2W = d_in[15]; const void* tg2b = d_in[16];
  const void* linW = d_in[17]; const void* linb = d_in[18];

  char* base = (char*)d_ws; size_t off = 0;
  auto alloc = [&](size_t bytes)->void*{
    void* r = base + off; off = (off + bytes + 255) & ~(size_t)255; return r;
  };
  int* flags                 = (int*)alloc(16);
  float* kmx                 = (float*)alloc(16);
  unsigned long long* bm     = (unsigned long long*)alloc((size_t)MWORDS*8);
  unsigned short* x_bf       = (unsigned short*)alloc((size_t)N_NODES*DIN*2);
  unsigned short* W1T        = (unsigned short*)alloc((size_t)2*DHEAD*DIN*2);
  unsigned short* W2T        = (unsigned short*)alloc((size_t)2*DHEAD*HID*2);
  unsigned short* mlp1WT     = (unsigned short*)alloc((size_t)2*HID*HID*2);
  unsigned short* mlp2WT     = (unsigned short*)alloc((size_t)2*HID*DOUT*2);
  float* smallf              = (float*)alloc(10*1024*4);
  float* v_f32           = (float*)alloc((size_t)2*N_NODES*DHEAD*4);
  unsigned short* vT_bf  = (unsigned short*)alloc((size_t)2*DHEAD*N_NODES*2);
  float* qv = (float*)alloc((size_t)2*N_NODES*4);
  float* kv = (float*)alloc((size_t)2*N_NODES*4);
  float* mv = (float*)alloc((size_t)2*N_NODES*4);
  float* dv = (float*)alloc((size_t)2*N_NODES*4);
  unsigned short* h_bf     = (unsigned short*)alloc((size_t)N_NODES*HID*2);
  unsigned short* embed_bf = (unsigned short*)alloc((size_t)N_NODES*HID*2);
  unsigned short* mid2     = (unsigned short*)alloc((size_t)2*N_NODES*HID*2);
  float* tfg = (float*)alloc((size_t)2*N_NODES*DOUT*4);
  size_t base_need = off;
  int ws_ok = (ws_size >= base_need) ? 1 : 0;

  // param views into smallf
  float* a1f  = smallf + 0*1024;
  float* b1f  = smallf + 1*1024;
  float* a2f  = smallf + 2*1024;
  float* b2f  = smallf + 3*1024;
  float* tf1bf = smallf + 4*1024;
  float* tf2bf = smallf + 5*1024;
  float* linWf = smallf + 8*1024;
  float* linbf = smallf + 9*1024;

  // j-split ladder: 4 preferred (8 showed no gain, 2x partial traffic)
  size_t per_slice = (size_t)2*N_NODES*DHEAD*4 + (size_t)2*N_NODES*4;
  int slices = 0;
  if      (ws_size >= base_need + 4*per_slice + 1024) slices = 4;
  else if (ws_size >= base_need + 2*per_slice + 1024) slices = 2;
  else if (ws_size >= base_need + 1*per_slice + 1024) slices = 1;
  float* part   = (slices > 0) ? (float*)alloc((size_t)slices*2*N_NODES*DHEAD*4) : nullptr;
  float* part_d = (slices > 0) ? (float*)alloc((size_t)slices*2*N_NODES*4) : nullptr;

  detect_kernel<<<1, 256, 0, stream>>>((const unsigned int*)x, (const unsigned int*)ts, flags);

  if (ws_ok){
    conv_bf16_kernel<<<(N_NODES*DIN)/256, 256, 0, stream>>>(x, x_bf, N_NODES*DIN, flags);
    conv_tr6_kernel<<<4608, 256, 0, stream>>>(W1, W2, tf1W, tg1W, tf2W, tg2W,
        W1T, W2T, mlp1WT, mlp1WT + (size_t)HID*HID, mlp2WT, mlp2WT + (size_t)HID*DOUT, flags);
    conv_small_kernel<<<40, 256, 0, stream>>>(a1, b1, a2, b2, tf1b, tf2b, tg1b, tg2b,
                                              linW, linb, smallf, flags);
    bitmask_kernel<<<2048, 256, 0, stream>>>(adj, bm);

    const unsigned char* mbytes = (const unsigned char*)bm;

    // ---- layer 1 ----
    gemm4_kernel<<<dim3(N_NODES/64, 4, 2), 256, 0, stream>>>(
        x_bf, 0, W1T, (long)DHEAD*DIN, DIN, DHEAD, nullptr, 0, 1.0f,
        v_f32, DHEAD, (long)N_NODES*DHEAD, nullptr, 0, 0,
        vT_bf, DHEAD, (long)DHEAD*N_NODES);
    qk_kernel<<<dim3(N_NODES/4, 2), 256, 0, stream>>>(v_f32, a1f, qv, kv);
    if (slices > 0){
      kmax_kernel<<<dim3(1, 2), 256, 0, stream>>>(kv, kmx);
      attn_part_kernel<<<(N_NODES/64)*2*slices, 256, 0, stream>>>(
          qv, kv, kmx, mbytes, vT_bf, part, part_d, (N_NODES/32)/slices, slices);
      attn_combine_kernel<<<dim3(N_NODES/4, 2), 256, 0, stream>>>(part, part_d, b1f, h_bf, 1, slices);
    } else {
      rowstat_kernel<<<dim3(N_NODES, 2), 256, 0, stream>>>(qv, kv, bm, mv, dv);
      attn_kernel<<<dim3(N_NODES/64, 2), 256, 0, stream>>>(qv, kv, mv, dv, mbytes, vT_bf, b1f, h_bf, 1);
    }

    // ---- layer 2 ----
    gemm4_kernel<<<dim3(N_NODES/64, 4, 2), 256, 0, stream>>>(
        h_bf, 0, W2T, (long)DHEAD*HID, HID, DHEAD, nullptr, 0, 1.0f,
        v_f32, DHEAD, (long)N_NODES*DHEAD, nullptr, 0, 0,
        vT_bf, DHEAD, (long)DHEAD*N_NODES);
    qk_kernel<<<dim3(N_NODES/4, 2), 256, 0, stream>>>(v_f32, a2f, qv, kv);
    if (slices > 0){
      kmax_kernel<<<dim3(1, 2), 256, 0, stream>>>(kv, kmx + 2);
      attn_part_kernel<<<(N_NODES/64)*2*slices, 256, 0, stream>>>(
          qv, kv, kmx + 2, mbytes, vT_bf, part, part_d, (N_NODES/32)/slices, slices);
      attn_combine_kernel<<<dim3(N_NODES/4, 2), 256, 0, stream>>>(part, part_d, b2f, embed_bf, 0, slices);
    } else {
      rowstat_kernel<<<dim3(N_NODES, 2), 256, 0, stream>>>(qv, kv, bm, mv, dv);
      attn_kernel<<<dim3(N_NODES/64, 2), 256, 0, stream>>>(qv, kv, mv, dv, mbytes, vT_bf, b2f, embed_bf, 0);
    }

    // ---- MLP heads: tf & tg batched via z ----
    gemm8_kernel<<<dim3(N_NODES/64, 4, 2), 256, 0, stream>>>(
        embed_bf, 0, mlp1WT, (long)HID*HID, HID, HID, tf1bf, 2048, 0.01f,
        nullptr, 0, 0, mid2, HID, (long)N_NODES*HID, nullptr, 0, 0);
    gemm4_kernel<<<dim3(N_NODES/64, 2, 2), 256, 0, stream>>>(
        mid2, (long)N_NODES*HID, mlp2WT, (long)HID*DOUT, HID, DOUT, tf2bf, 2048, 0.01f,
        tfg, DOUT, (long)N_NODES*DOUT, nullptr, 0, 0, nullptr, 0, 0);

    // ---- gather + linear (float32 output) ----
    final_kernel<<<NPAIRS/4, 256, 0, stream>>>(ts, tfg, tfg + (size_t)N_NODES*DOUT,
                                               linWf, linbf, (float*)d_out, flags);
  }
}